// Round 6
// baseline (803.356 us; speedup 1.0000x reference)
//
#include <hip/hip_runtime.h>
#include <hip/hip_bf16.h>
#include <math.h>

#define B_   16
#define L_   2048
#define D_   128
#define H_   4
#define NL_  4
#define DK_  32
#define DFF_ 256
#define INTD_ 11
#define F_OUT 129
#define DM_  16
#define FMINV (-3.402823466e38f)
#define LOG2E 1.4426950408889634f

#define BL_  (B_*L_)      // 32768
#define SZ_X (BL_*D_)     // 4194304 floats

#define WT_Q 0
#define WT_K 16384
#define WT_V 32768
#define WT_O 49152
#define WT_1 65536
#define WT_2 98304
#define WT_TOT 131072

typedef __attribute__((ext_vector_type(8))) short bf16x8;
typedef __attribute__((ext_vector_type(4))) float f32x4;

#if __has_builtin(__builtin_amdgcn_exp2f)
#define EXP2F(x) __builtin_amdgcn_exp2f(x)
#else
#define EXP2F(x) __expf(0.69314718055994531f*(x))
#endif

static __device__ __forceinline__ short f2bf(float x) {
    union { __hip_bfloat16 h; short s; } u;
    u.h = __float2bfloat16(x);
    return u.s;
}
static __device__ __forceinline__ float bf2f(short s) {
    union { __hip_bfloat16 h; short t; } u;
    u.t = s;
    return __bfloat162float(u.h);
}
static __device__ __forceinline__ void split2(float v, short& h, short& l) {
    h = f2bf(v); l = f2bf(v - bf2f(h));
}
static __device__ __forceinline__ void split_trunc(float v, short& h, short& l) {
    unsigned u = __float_as_uint(v);
    h = (short)(u >> 16);
    float r = v - __uint_as_float(u & 0xffff0000u);
    l = (short)(__float_as_uint(r) >> 16);
}
// Raw workgroup barrier draining LDS only: outstanding GLOBAL loads/stores
// stay in flight (compiler's __syncthreads would emit vmcnt(0) too).
static __device__ __forceinline__ void bar_lgkm() {
    asm volatile("s_waitcnt lgkmcnt(0)" ::: "memory");
    __builtin_amdgcn_s_barrier();
}

// ---------------------------------------------------------------------------
// Mask compaction + x tail-zero: pos, kcount, cfm; zeroes x rows [Kb,ceil64).
// ---------------------------------------------------------------------------
__global__ __launch_bounds__(256)
void compact_kernel(const int* __restrict__ mask, int* __restrict__ pos,
                    int* __restrict__ kcount, float* __restrict__ cfm,
                    float* __restrict__ x)
{
    int b = blockIdx.x, t = threadIdx.x;
    int lane = t & 63, w = t >> 6;
    __shared__ int wsum[4];
    __shared__ int tot_s;
    int mv[8], loc[8], s = 0;
#pragma unroll
    for (int i = 0; i < 8; ++i) {
        mv[i] = mask[b*L_ + t*8 + i];
        loc[i] = s;
        s += mv[i];
    }
    int v = s;
#pragma unroll
    for (int d = 1; d < 64; d <<= 1) {
        int y = __shfl_up(v, d);
        if (lane >= d) v += y;
    }
    int excl = v - s;
    if (lane == 63) wsum[w] = v;
    __syncthreads();
    int wbase = 0;
    for (int i = 0; i < w; ++i) wbase += wsum[i];
    int base = wbase + excl;
#pragma unroll
    for (int i = 0; i < 8; ++i)
        pos[b*L_ + t*8 + i] = mv[i] ? (base + loc[i]) : -1;
    if (t == 255) { kcount[b] = base + s; tot_s = base + s; }
    __syncthreads();
    int tot = tot_s;
    for (int l = t; l < L_; l += 256) cfm[b*L_ + l] = (l < tot) ? 0.0f : FMINV;
    int end = (tot + 63) & ~63;
    int nz = (end - tot) * D_;
    for (int i = t; i < nz; i += 256)
        x[((size_t)(b*2048 + tot))*D_ + i] = 0.0f;
}

// ---------------------------------------------------------------------------
// Embedding with compaction
// ---------------------------------------------------------------------------
__global__ __launch_bounds__(128)
void embed_kernel(const float* __restrict__ values, const float* __restrict__ times,
                  const int* __restrict__ variables, const int* __restrict__ pos,
                  const float* __restrict__ W1t, const float* __restrict__ b1t,
                  const float* __restrict__ W2t,
                  const float* __restrict__ W1v, const float* __restrict__ b1v,
                  const float* __restrict__ W2v,
                  const float* __restrict__ var_table, float* __restrict__ x)
{
    int bl = blockIdx.x;
    int p  = pos[bl];
    if (p < 0) return;
    int t  = threadIdx.x;
    __shared__ float th[INTD_], vh[INTD_];
    if (t < INTD_)                th[t]    = tanhf(times[bl]  * W1t[t]    + b1t[t]);
    if (t >= 64 && t < 64+INTD_)  vh[t-64] = tanhf(values[bl] * W1v[t-64] + b1v[t-64]);
    __syncthreads();
    int var = variables[bl];
    float acc = var_table[var*D_ + t];
#pragma unroll
    for (int i = 0; i < INTD_; ++i)
        acc += th[i]*W2t[i*D_ + t] + vh[i]*W2v[i*D_ + t];
    x[((size_t)((bl >> 11)*2048 + p))*D_ + t] = acc;
}

// ---------------------------------------------------------------------------
// Weight pre-split: all 4 layers + Wf appended at offset NL_*WT_TOT.
// ---------------------------------------------------------------------------
__global__ __launch_bounds__(256)
void split_all_kernel(const float* __restrict__ Wq, const float* __restrict__ Wk,
                      const float* __restrict__ Wv, const float* __restrict__ Wo,
                      const float* __restrict__ W1, const float* __restrict__ W2,
                      const float* __restrict__ Wf,
                      short* __restrict__ hi, short* __restrict__ lo)
{
    int gidx = blockIdx.x*256 + threadIdx.x;
    float v;
    if (gidx < NL_*131072) {
        int layer = gidx >> 17;
        int idx   = gidx & 131071;
        if (idx < 49152) {
            int which = idx >> 14;
            int r = idx & 16383;
            int col = r >> 7, k = r & 127;
            int h = col >> 5, e = col & 31;
            const float* src = ((which == 0) ? Wq : (which == 1) ? Wk : Wv)
                               + (size_t)layer*H_*D_*DK_;
            v = src[(h*D_ + k)*DK_ + e];
        } else if (idx < 65536) {
            int r = idx - 49152;
            int col = r >> 7, k = r & 127;
            v = Wo[(size_t)layer*D_*D_ + k*D_ + col];
        } else if (idx < 98304) {
            int r = idx - 65536;
            int col = r >> 7, k = r & 127;
            v = W1[(size_t)layer*D_*DFF_ + k*DFF_ + col];
        } else {
            int r = idx - 98304;
            int col = r >> 8, k = r & 255;
            v = W2[(size_t)layer*DFF_*D_ + k*D_ + col];
        }
    } else {
        int r = gidx - NL_*131072;      // Wf: 16384 elems, [col][K]
        int col = r >> 7, k = r & 127;
        v = Wf[k*D_ + col];
    }
    short h2, l2; split2(v, h2, l2);
    hi[gidx] = h2; lo[gidx] = l2;
}

// ---------------------------------------------------------------------------
// Fused QKV GEMM (layer 0 only), one weight stream per block (grid.y=3).
// ---------------------------------------------------------------------------
__global__ __launch_bounds__(256)
void gemm_qkv_fused(const float* __restrict__ A, const short* __restrict__ Whi,
                    const short* __restrict__ Wlo, const int* __restrict__ kcount,
                    float* __restrict__ qout,
                    short* __restrict__ khi, short* __restrict__ klo,
                    short* __restrict__ vhiT, short* __restrict__ vloT)
{
    const int row0 = blockIdx.x * 64;
    const int bb = row0 >> 11;
    if ((row0 & 2047) >= ((kcount[bb] + 63) & ~63)) return;
    const int sec = blockIdx.y;

    __shared__ short Ahi[64*136];
    __shared__ short Alo[64*136];
    const int t = threadIdx.x;
    const int w = t >> 6, lane = t & 63;
    const int m = lane & 15, qd = lane >> 4;

#pragma unroll
    for (int i = 0; i < 8; ++i) {
        int r = (t >> 5) + 8*i;
        int c = (t & 31) * 4;
        float4 av = *(const float4*)(A + (size_t)(row0 + r)*D_ + c);
        short4 hi4, lo4;
        split2(av.x, hi4.x, lo4.x);
        split2(av.y, hi4.y, lo4.y);
        split2(av.z, hi4.z, lo4.z);
        split2(av.w, hi4.w, lo4.w);
        *(short4*)&Ahi[r*136 + c] = hi4;
        *(short4*)&Alo[r*136 + c] = lo4;
    }
    __syncthreads();

    const short* Wh = Whi + sec*16384;
    const short* Wl = Wlo + sec*16384;
    f32x4 acc[4][2];
#pragma unroll
    for (int r4 = 0; r4 < 4; ++r4)
#pragma unroll
        for (int j = 0; j < 2; ++j) acc[r4][j] = (f32x4){0,0,0,0};

#pragma unroll
    for (int ks = 0; ks < 4; ++ks) {
        bf16x8 wh[2], wl[2];
#pragma unroll
        for (int j = 0; j < 2; ++j) {
            size_t wi = (size_t)(32*w + 16*j + m)*D_ + 32*ks + 8*qd;
            wh[j] = *(const bf16x8*)(Wh + wi);
            wl[j] = *(const bf16x8*)(Wl + wi);
        }
#pragma unroll
        for (int r4 = 0; r4 < 4; ++r4) {
            bf16x8 ah = *(const bf16x8*)&Ahi[(16*r4 + m)*136 + 32*ks + 8*qd];
            bf16x8 al = *(const bf16x8*)&Alo[(16*r4 + m)*136 + 32*ks + 8*qd];
#pragma unroll
            for (int j = 0; j < 2; ++j) {
                acc[r4][j] = __builtin_amdgcn_mfma_f32_16x16x32_bf16(wh[j], ah, acc[r4][j], 0, 0, 0);
                acc[r4][j] = __builtin_amdgcn_mfma_f32_16x16x32_bf16(wh[j], al, acc[r4][j], 0, 0, 0);
                acc[r4][j] = __builtin_amdgcn_mfma_f32_16x16x32_bf16(wl[j], ah, acc[r4][j], 0, 0, 0);
            }
        }
    }

#pragma unroll
    for (int r4 = 0; r4 < 4; ++r4) {
        int row = row0 + 16*r4 + m;
        int l = row & 2047;
#pragma unroll
        for (int j = 0; j < 2; ++j) {
            int col = 32*w + 16*j + 4*qd;
            f32x4 v = acc[r4][j];
            if (sec == 0) {
                float4 sv = {v[0], v[1], v[2], v[3]};
                *(float4*)(qout + (size_t)row*D_ + col) = sv;
            } else if (sec == 1) {
                size_t idx = ((size_t)((bb*4 + w)*2048 + l))*32 + (col & 31);
                short4 hi4, lo4;
                split2(v[0], hi4.x, lo4.x);
                split2(v[1], hi4.y, lo4.y);
                split2(v[2], hi4.z, lo4.z);
                split2(v[3], hi4.w, lo4.w);
                *(short4*)(khi + idx) = hi4;
                *(short4*)(klo + idx) = lo4;
            } else {
                size_t basep = (size_t)(bb*4 + w)*32;
#pragma unroll
                for (int e = 0; e < 4; ++e) {
                    int d = 16*j + 4*qd + e;
                    short hh, ll; split2(v[e], hh, ll);
                    vhiT[(basep + d)*2048 + l] = hh;
                    vloT[(basep + d)*2048 + l] = ll;
                }
            }
        }
    }
}

// ---------------------------------------------------------------------------
// SPLIT-K MFMA flash attention — R3's best-measured version (95.7 µs):
// double-buffered K/V LDS + ONE raw lgkm-only barrier per tile; prefetch
// global loads stay in flight across the barrier. LDS 40960 B, VGPR ~84.
// (R5's single-buffer/2-barrier variant measured slower; occupancy proved
// NOT resource-capped, so the lower LDS bought nothing.)
// ---------------------------------------------------------------------------
__global__ __launch_bounds__(256)
void attn_mfma_kernel(const float* __restrict__ q,
                      const short* __restrict__ khi, const short* __restrict__ klo,
                      const short* __restrict__ vhiT, const short* __restrict__ vloT,
                      const int* __restrict__ kcount, const float* __restrict__ cfm,
                      float* __restrict__ opart, float* __restrict__ mlm,
                      float* __restrict__ mll)
{
    (void)cfm;
    __shared__ short KhiS[2][2048];   // [buf][key*32 + dim]   rows 64B, aligned
    __shared__ short KloS[2][2048];
    __shared__ short Vthi[2][2048];   // [buf][d*64 + swz-chunk] rows 128B
    __shared__ short Vtlo[2][2048];
    __shared__ short Ps[4][1024];     // per-wave [m*64 + swz-chunk]

    const int t    = threadIdx.x;
    const int w    = t >> 6;
    const int lane = t & 63;
    const int m    = lane & 15;
    const int qd   = lane >> 4;
    const int qt = blockIdx.x, b = blockIdx.z;
    const int h = blockIdx.y & 3, half = blockIdx.y >> 2;

    const int Kb = kcount[b];
    if (qt*64 >= Kb) return;
    const int nt = (Kb + 63) >> 6;
    const int ntH = (nt + 1) >> 1;
    const int kt0 = half * ntH;
    const int kt1 = (kt0 + ntH < nt) ? (kt0 + ntH) : nt;
    const size_t mlbase = (((size_t)(b*4 + h))*2 + half)*2048;

    if (kt0 >= kt1) {
        if (lane < 16) {
            mlm[mlbase + qt*64 + 16*w + lane] = FMINV;
            mll[mlbase + qt*64 + 16*w + lane] = 0.0f;
        }
        return;
    }

    const size_t hd = ((size_t)(b*4 + h))*2048*32;
    const int vd = t >> 3;
    const int vk = t & 7;
    const size_t vbase = ((size_t)(b*4 + h)*32 + vd)*2048 + vk*8;
    const int vw_off = vd*64 + ((vk ^ (vd & 7)) << 3);   // swizzled V slot

    const int qrow = qt*64 + 16*w + m;
    const float* qp = q + ((size_t)(b*L_ + qrow))*D_ + h*DK_ + 8*qd;
    float qf[8];
    *(float4*)&qf[0] = *(const float4*)qp;
    *(float4*)&qf[4] = *(const float4*)(qp + 4);
    bf16x8 qhi, qlo;
#pragma unroll
    for (int j = 0; j < 8; ++j) {
        float qs = qf[j] * LOG2E;
        short hs = f2bf(qs);
        qhi[j] = hs;
        qlo[j] = f2bf(qs - bf2f(hs));
    }

    bf16x8 pkh, pkl, pvh, pvl;
    {
        const size_t gk = hd + (size_t)kt0*64*32 + t*8;
        pkh = *(const bf16x8*)(khi + gk);
        pkl = *(const bf16x8*)(klo + gk);
        pvh = *(const bf16x8*)(vhiT + vbase + (size_t)kt0*64);
        pvl = *(const bf16x8*)(vloT + vbase + (size_t)kt0*64);
    }

    float m_old = -INFINITY, l_run = 0.0f;
    f32x4 o_acc[2] = {{0,0,0,0},{0,0,0,0}};

    for (int kt = kt0; kt < kt1; ++kt) {
        const int buf = kt & 1;
        // ---- stage current tile into LDS[buf] (other waves may still be
        //      computing on LDS[buf^1] — no pre-barrier needed) ----
        *(bf16x8*)&KhiS[buf][t*8] = pkh;
        *(bf16x8*)&KloS[buf][t*8] = pkl;
        *(bf16x8*)&Vthi[buf][vw_off] = pvh;
        *(bf16x8*)&Vtlo[buf][vw_off] = pvl;
        // ---- issue next-tile prefetch; stays in flight across the barrier ----
        if (kt + 1 < kt1) {
            const size_t gk = hd + (size_t)(kt+1)*64*32 + t*8;
            pkh = *(const bf16x8*)(khi + gk);
            pkl = *(const bf16x8*)(klo + gk);
            pvh = *(const bf16x8*)(vhiT + vbase + (size_t)(kt+1)*64);
            pvl = *(const bf16x8*)(vloT + vbase + (size_t)(kt+1)*64);
        }
        // ---- single barrier: drain LDS only (NOT vmcnt) ----
        bar_lgkm();
        __builtin_amdgcn_sched_barrier(0);

        // ---- QK^T ----
        f32x4 sf[4];
#pragma unroll
        for (int k4 = 0; k4 < 4; ++k4) {
            bf16x8 ka = *(const bf16x8*)&KhiS[buf][(16*k4 + m)*32 + 8*qd];
            bf16x8 kl = *(const bf16x8*)&KloS[buf][(16*k4 + m)*32 + 8*qd];
            f32x4 c = {0,0,0,0};
            c = __builtin_amdgcn_mfma_f32_16x16x32_bf16(ka, qhi, c, 0, 0, 0);
            c = __builtin_amdgcn_mfma_f32_16x16x32_bf16(ka, qlo, c, 0, 0, 0);
            c = __builtin_amdgcn_mfma_f32_16x16x32_bf16(kl, qhi, c, 0, 0, 0);
            sf[k4] = c;
        }

        // ---- mask: only the last tile has invalid columns ----
        float sv[16];
        if (kt == nt - 1) {
            const int rel = Kb - kt*64;
#pragma unroll
            for (int k4 = 0; k4 < 4; ++k4)
#pragma unroll
                for (int e = 0; e < 4; ++e)
                    sv[4*k4+e] = sf[k4][e] +
                        (((16*k4 + 4*qd + e) < rel) ? 0.0f : FMINV);
        } else {
#pragma unroll
            for (int k4 = 0; k4 < 4; ++k4)
#pragma unroll
                for (int e = 0; e < 4; ++e)
                    sv[4*k4+e] = sf[k4][e];
        }

        // log-depth max tree
        float mx8[8];
#pragma unroll
        for (int j = 0; j < 8; ++j) mx8[j] = fmaxf(sv[2*j], sv[2*j+1]);
#pragma unroll
        for (int j = 0; j < 4; ++j) mx8[j] = fmaxf(mx8[j], mx8[j+4]);
        float tmax = fmaxf(fmaxf(mx8[0], mx8[1]), fmaxf(mx8[2], mx8[3]));
        tmax = fmaxf(tmax, __shfl_xor(tmax, 16));
        tmax = fmaxf(tmax, __shfl_xor(tmax, 32));
        float mnew  = fmaxf(m_old, tmax);
        float alpha = EXP2F(m_old - mnew);
        float pj[16];
        short pbh[16], pbl[16];
#pragma unroll
        for (int j = 0; j < 16; ++j) {
            float p = EXP2F(sv[j] - mnew);
            pj[j] = p;
            split_trunc(p, pbh[j], pbl[j]);
        }
        // log-depth sum tree
        float ps8[8];
#pragma unroll
        for (int j = 0; j < 8; ++j) ps8[j] = pj[2*j] + pj[2*j+1];
#pragma unroll
        for (int j = 0; j < 4; ++j) ps8[j] = ps8[j] + ps8[j+4];
        float psum = (ps8[0] + ps8[1]) + (ps8[2] + ps8[3]);
        psum += __shfl_xor(psum, 16);
        psum += __shfl_xor(psum, 32);
        l_run = l_run * alpha + psum;
        m_old = mnew;

        // ---- write Phi (swizzled chunks, 8B-aligned short4) ----
#pragma unroll
        for (int k4 = 0; k4 < 4; ++k4) {
            short4 s4h;
            s4h.x = pbh[4*k4+0]; s4h.y = pbh[4*k4+1]; s4h.z = pbh[4*k4+2]; s4h.w = pbh[4*k4+3];
            int chunk = 2*k4 + (qd >> 1);
            int po = m*64 + ((chunk ^ (m & 7)) << 3) + ((qd & 1) << 2);
            *(short4*)&Ps[w][po] = s4h;
        }

        // ---- O rescale: alpha lives per q-row m; rows of o_acc are 4qd+r ----
        {
            float a0 = __shfl(alpha, 4*qd + 0);
            float a1 = __shfl(alpha, 4*qd + 1);
            float a2 = __shfl(alpha, 4*qd + 2);
            float a3 = __shfl(alpha, 4*qd + 3);
            o_acc[0][0]*=a0; o_acc[0][1]*=a1; o_acc[0][2]*=a2; o_acc[0][3]*=a3;
            o_acc[1][0]*=a0; o_acc[1][1]*=a1; o_acc[1][2]*=a2; o_acc[1][3]*=a3;
        }
        // ---- pass 1: Phi·Vhi + Phi·Vlo ----
#pragma unroll
        for (int s = 0; s < 2; ++s) {
#pragma unroll
            for (int tp = 0; tp < 2; ++tp) {
                bf16x8 pah = *(const bf16x8*)&Ps[w][m*64 + (((4*s + qd) ^ (m & 7)) << 3)];
                int vr = (16*tp + m)*64 + (((4*s + qd) ^ (m & 7)) << 3);
                bf16x8 vh = *(const bf16x8*)&Vthi[buf][vr];
                bf16x8 vl = *(const bf16x8*)&Vtlo[buf][vr];
                o_acc[tp] = __builtin_amdgcn_mfma_f32_16x16x32_bf16(pah, vh, o_acc[tp], 0, 0, 0);
                o_acc[tp] = __builtin_amdgcn_mfma_f32_16x16x32_bf16(pah, vl, o_acc[tp], 0, 0, 0);
            }
        }
        // ---- overwrite with Plo (wave-private, in-order DS => WAR-safe) ----
#pragma unroll
        for (int k4 = 0; k4 < 4; ++k4) {
            short4 s4l;
            s4l.x = pbl[4*k4+0]; s4l.y = pbl[4*k4+1]; s4l.z = pbl[4*k4+2]; s4l.w = pbl[4*k4+3];
            int chunk = 2*k4 + (qd >> 1);
            int po = m*64 + ((chunk ^ (m & 7)) << 3) + ((qd & 1) << 2);
            *(short4*)&Ps[w][po] = s4l;
        }
        // ---- pass 2: Plo·Vhi ----
#pragma unroll
        for (int s = 0; s < 2; ++s) {
#pragma unroll
            for (int tp = 0; tp < 2; ++tp) {
                bf16x8 pal = *(const bf16x8*)&Ps[w][m*64 + (((4*s + qd) ^ (m & 7)) << 3)];
                int vr = (16*tp + m)*64 + (((4*s + qd) ^ (m & 7)) << 3);
                bf16x8 vh = *(const bf16x8*)&Vthi[buf][vr];
                o_acc[tp] = __builtin_amdgcn_mfma_f32_16x16x32_bf16(pal, vh, o_acc[tp], 0, 0, 0);
            }
        }
    }

    if (lane < 16) {
        mlm[mlbase + qt*64 + 16*w + lane] = m_old;
        mll[mlbase + qt*64 + 16*w + lane] = l_run;
    }
    float* ob = opart + (size_t)half*SZ_X;
#pragma unroll
    for (int tp = 0; tp < 2; ++tp)
#pragma unroll
        for (int r = 0; r < 4; ++r)
            ob[((size_t)(b*L_ + qt*64 + 16*w + 4*qd + r))*D_ + h*DK_ + 16*tp + m] =
                o_acc[tp][r];
}

// ---------------------------------------------------------------------------
// R6 FUSED LAYER TAIL: split-K merge + Wo GEMM + resid (xnew kept in REGS,
// intermediate x never written) + FFN1/GELU/FFN2 with hb entirely in LDS
// (two K=128 half-passes reusing the Ahi/Alo staging buffers) + final
// x write + [TAIL=0: next-layer QKV | TAIL=1: fusion att dot].
// Eliminates per layer: hb 32MB wr + 32MB rd, intermediate-x 16MB wr +
// 16MB rd, and one kernel launch. Same FLOPs. ~10 lgkm-only barriers.
// ---------------------------------------------------------------------------
template<int TAIL>
__global__ __launch_bounds__(256)
void layer_fused_kernel(const float* __restrict__ opart, const float* __restrict__ mlm,
                        const float* __restrict__ mll,
                        const short* __restrict__ WhiO, const short* __restrict__ WloO,
                        const short* __restrict__ Whi1, const short* __restrict__ Wlo1,
                        const float* __restrict__ b1,
                        const short* __restrict__ Whi2, const short* __restrict__ Wlo2,
                        const float* __restrict__ b2,
                        const short* __restrict__ WhiN, const short* __restrict__ WloN,
                        const float* __restrict__ bfv, const float* __restrict__ uf,
                        const float* __restrict__ cfm,
                        const int* __restrict__ kcount, float* __restrict__ x,
                        float* __restrict__ qout,
                        short* __restrict__ khi, short* __restrict__ klo,
                        short* __restrict__ vhiT, short* __restrict__ vloT,
                        float* __restrict__ attb)
{
    const int row0 = blockIdx.x * 64;
    const int bb = row0 >> 11;
    if ((row0 & 2047) >= ((kcount[bb] + 63) & ~63)) return;

    __shared__ short Ahi[64*136];
    __shared__ short Alo[64*136];
    __shared__ float part[64][16];
    const int t = threadIdx.x;
    const int w = t >> 6, lane = t & 63;
    const int m = lane & 15, qd = lane >> 4;

    // ---- stage merged O hi/lo ----
#pragma unroll
    for (int i = 0; i < 8; ++i) {
        int r = (t >> 5) + 8*i;
        int c = (t & 31) * 4;
        int row = row0 + r;
        int l = row & 2047;
        int h = c >> 5;
        size_t i0 = (((size_t)(bb*4 + h))*2 + 0)*2048 + l;
        size_t i1 = i0 + 2048;
        float m0 = mlm[i0], m1 = mlm[i1];
        float l0 = mll[i0], l1 = mll[i1];
        float M  = fmaxf(m0, m1);
        float w0 = EXP2F(m0 - M), w1 = EXP2F(m1 - M);
        float inv = 1.0f / (l0*w0 + l1*w1);
        float s0 = w0 * inv, s1 = w1 * inv;
        float4 o0 = *(const float4*)(opart + (size_t)row*D_ + c);
        float4 o1 = *(const float4*)(opart + (size_t)(BL_ + row)*D_ + c);
        float4 av;
        av.x = s0*o0.x + s1*o1.x;
        av.y = s0*o0.y + s1*o1.y;
        av.z = s0*o0.z + s1*o1.z;
        av.w = s0*o0.w + s1*o1.w;
        short4 hi4, lo4;
        split2(av.x, hi4.x, lo4.x);
        split2(av.y, hi4.y, lo4.y);
        split2(av.z, hi4.z, lo4.z);
        split2(av.w, hi4.w, lo4.w);
        *(short4*)&Ahi[r*136 + c] = hi4;
        *(short4*)&Alo[r*136 + c] = lo4;
    }
    bar_lgkm();

    // ---- Wo matmul -> xnew (REGS; never written to global) ----
    f32x4 xnew[4][2];
#pragma unroll
    for (int r4 = 0; r4 < 4; ++r4)
#pragma unroll
        for (int j = 0; j < 2; ++j) xnew[r4][j] = (f32x4){0,0,0,0};
#pragma unroll
    for (int ks = 0; ks < 4; ++ks) {
        bf16x8 wh[2], wl[2];
#pragma unroll
        for (int j = 0; j < 2; ++j) {
            size_t wi = (size_t)(32*w + 16*j + m)*D_ + 32*ks + 8*qd;
            wh[j] = *(const bf16x8*)(WhiO + wi);
            wl[j] = *(const bf16x8*)(WloO + wi);
        }
#pragma unroll
        for (int r4 = 0; r4 < 4; ++r4) {
            bf16x8 ah = *(const bf16x8*)&Ahi[(16*r4 + m)*136 + 32*ks + 8*qd];
            bf16x8 al = *(const bf16x8*)&Alo[(16*r4 + m)*136 + 32*ks + 8*qd];
#pragma unroll
            for (int j = 0; j < 2; ++j) {
                xnew[r4][j] = __builtin_amdgcn_mfma_f32_16x16x32_bf16(wh[j], ah, xnew[r4][j], 0, 0, 0);
                xnew[r4][j] = __builtin_amdgcn_mfma_f32_16x16x32_bf16(wh[j], al, xnew[r4][j], 0, 0, 0);
                xnew[r4][j] = __builtin_amdgcn_mfma_f32_16x16x32_bf16(wl[j], ah, xnew[r4][j], 0, 0, 0);
            }
        }
    }
    // + residual (read old x; do NOT write intermediate x)
#pragma unroll
    for (int r4 = 0; r4 < 4; ++r4) {
        int row = row0 + 16*r4 + m;
#pragma unroll
        for (int j = 0; j < 2; ++j) {
            int col = 32*w + 16*j + 4*qd;
            float4 rv = *(const float4*)(x + (size_t)row*D_ + col);
            xnew[r4][j][0] += rv.x; xnew[r4][j][1] += rv.y;
            xnew[r4][j][2] += rv.z; xnew[r4][j][3] += rv.w;
        }
    }
    bar_lgkm();   // Wo-phase LDS reads done

    // ---- restage xnew hi/lo (helper lambda-free, inlined twice below) ----
#pragma unroll
    for (int r4 = 0; r4 < 4; ++r4)
#pragma unroll
        for (int j = 0; j < 2; ++j) {
            int col = 32*w + 16*j + 4*qd;
            short4 hi4, lo4;
            split2(xnew[r4][j][0], hi4.x, lo4.x);
            split2(xnew[r4][j][1], hi4.y, lo4.y);
            split2(xnew[r4][j][2], hi4.z, lo4.z);
            split2(xnew[r4][j][3], hi4.w, lo4.w);
            *(short4*)&Ahi[(16*r4 + m)*136 + col] = hi4;
            *(short4*)&Alo[(16*r4 + m)*136 + col] = lo4;
        }
    bar_lgkm();

    // ---- FFN over two K=128 halves; hb never leaves the CU ----
    f32x4 acc2[4][2];
#pragma unroll
    for (int r4 = 0; r4 < 4; ++r4)
#pragma unroll
        for (int j = 0; j < 2; ++j) acc2[r4][j] = (f32x4){0,0,0,0};

#pragma unroll
    for (int half = 0; half < 2; ++half) {
        // FFN1: output cols [128*half, 128*half+128)
        f32x4 a2[4][2];
#pragma unroll
        for (int r4 = 0; r4 < 4; ++r4)
#pragma unroll
            for (int j = 0; j < 2; ++j) a2[r4][j] = (f32x4){0,0,0,0};
#pragma unroll
        for (int ks = 0; ks < 4; ++ks) {
            bf16x8 wh[2], wl[2];
#pragma unroll
            for (int j = 0; j < 2; ++j) {
                size_t wi = (size_t)(128*half + 32*w + 16*j + m)*D_ + 32*ks + 8*qd;
                wh[j] = *(const bf16x8*)(Whi1 + wi);
                wl[j] = *(const bf16x8*)(Wlo1 + wi);
            }
#pragma unroll
            for (int r4 = 0; r4 < 4; ++r4) {
                bf16x8 ah = *(const bf16x8*)&Ahi[(16*r4 + m)*136 + 32*ks + 8*qd];
                bf16x8 al = *(const bf16x8*)&Alo[(16*r4 + m)*136 + 32*ks + 8*qd];
#pragma unroll
                for (int j = 0; j < 2; ++j) {
                    a2[r4][j] = __builtin_amdgcn_mfma_f32_16x16x32_bf16(wh[j], ah, a2[r4][j], 0, 0, 0);
                    a2[r4][j] = __builtin_amdgcn_mfma_f32_16x16x32_bf16(wh[j], al, a2[r4][j], 0, 0, 0);
                    a2[r4][j] = __builtin_amdgcn_mfma_f32_16x16x32_bf16(wl[j], ah, a2[r4][j], 0, 0, 0);
                }
            }
        }
        // GELU + bias
#pragma unroll
        for (int r4 = 0; r4 < 4; ++r4)
#pragma unroll
            for (int j = 0; j < 2; ++j) {
                int col = 128*half + 32*w + 16*j + 4*qd;
                float4 bv = *(const float4*)(b1 + col);
                a2[r4][j][0] += bv.x; a2[r4][j][1] += bv.y;
                a2[r4][j][2] += bv.z; a2[r4][j][3] += bv.w;
#pragma unroll
                for (int e = 0; e < 4; ++e)
                    a2[r4][j][e] = 0.5f * a2[r4][j][e] *
                                   (1.0f + erff(a2[r4][j][e] * 0.70710678118654752f));
            }
        bar_lgkm();   // all waves done reading current Ahi/Alo staging
        // restage GELU hi/lo (local cols 0..127)
#pragma unroll
        for (int r4 = 0; r4 < 4; ++r4)
#pragma unroll
            for (int j = 0; j < 2; ++j) {
                int lc = 32*w + 16*j + 4*qd;
                short4 hi4, lo4;
                split2(a2[r4][j][0], hi4.x, lo4.x);
                split2(a2[r4][j][1], hi4.y, lo4.y);
                split2(a2[r4][j][2], hi4.z, lo4.z);
                split2(a2[r4][j][3], hi4.w, lo4.w);
                *(short4*)&Ahi[(16*r4 + m)*136 + lc] = hi4;
                *(short4*)&Alo[(16*r4 + m)*136 + lc] = lo4;
            }
        bar_lgkm();
        // FFN2 accumulate over this K-half
#pragma unroll
        for (int ks = 0; ks < 4; ++ks) {
            bf16x8 wh[2], wl[2];
#pragma unroll
            for (int j = 0; j < 2; ++j) {
                size_t wi = (size_t)(32*w + 16*j + m)*DFF_ + 128*half + 32*ks + 8*qd;
                wh[j] = *(const bf16x8*)(Whi2 + wi);
                wl[j] = *(const bf16x8*)(Wlo2 + wi);
            }
#pragma unroll
            for (int r4 = 0; r4 < 4; ++r4) {
                bf16x8 ah = *(const bf16x8*)&Ahi[(16*r4 + m)*136 + 32*ks + 8*qd];
                bf16x8 al = *(const bf16x8*)&Alo[(16*r4 + m)*136 + 32*ks + 8*qd];
#pragma unroll
                for (int j = 0; j < 2; ++j) {
                    acc2[r4][j] = __builtin_amdgcn_mfma_f32_16x16x32_bf16(wh[j], ah, acc2[r4][j], 0, 0, 0);
                    acc2[r4][j] = __builtin_amdgcn_mfma_f32_16x16x32_bf16(wh[j], al, acc2[r4][j], 0, 0, 0);
                    acc2[r4][j] = __builtin_amdgcn_mfma_f32_16x16x32_bf16(wl[j], ah, acc2[r4][j], 0, 0, 0);
                }
            }
        }
        if (half == 0) {
            bar_lgkm();   // FFN2 half-0 reads done
            // re-restage xnew for FFN1 half-1
#pragma unroll
            for (int r4 = 0; r4 < 4; ++r4)
#pragma unroll
                for (int j = 0; j < 2; ++j) {
                    int col = 32*w + 16*j + 4*qd;
                    short4 hi4, lo4;
                    split2(xnew[r4][j][0], hi4.x, lo4.x);
                    split2(xnew[r4][j][1], hi4.y, lo4.y);
                    split2(xnew[r4][j][2], hi4.z, lo4.z);
                    split2(xnew[r4][j][3], hi4.w, lo4.w);
                    *(short4*)&Ahi[(16*r4 + m)*136 + col] = hi4;
                    *(short4*)&Alo[(16*r4 + m)*136 + col] = lo4;
                }
            bar_lgkm();
        }
    }

    // ---- epilogue: xfinal = acc2 + b2 + xnew; write x (once per layer) ----
#pragma unroll
    for (int r4 = 0; r4 < 4; ++r4) {
        int row = row0 + 16*r4 + m;
#pragma unroll
        for (int j = 0; j < 2; ++j) {
            int col = 32*w + 16*j + 4*qd;
            float4 bv = *(const float4*)(b2 + col);
            xnew[r4][j][0] += bv.x + acc2[r4][j][0];
            xnew[r4][j][1] += bv.y + acc2[r4][j][1];
            xnew[r4][j][2] += bv.z + acc2[r4][j][2];
            xnew[r4][j][3] += bv.w + acc2[r4][j][3];
            float4 sv = {xnew[r4][j][0], xnew[r4][j][1], xnew[r4][j][2], xnew[r4][j][3]};
            *(float4*)(x + (size_t)row*D_ + col) = sv;
        }
    }
    bar_lgkm();   // FFN2 half-1 LDS reads done; x stores stay in flight

    // ---- restage xfinal hi/lo ----
#pragma unroll
    for (int r4 = 0; r4 < 4; ++r4)
#pragma unroll
        for (int j = 0; j < 2; ++j) {
            int col = 32*w + 16*j + 4*qd;
            short4 hi4, lo4;
            split2(xnew[r4][j][0], hi4.x, lo4.x);
            split2(xnew[r4][j][1], hi4.y, lo4.y);
            split2(xnew[r4][j][2], hi4.z, lo4.z);
            split2(xnew[r4][j][3], hi4.w, lo4.w);
            *(short4*)&Ahi[(16*r4 + m)*136 + col] = hi4;
            *(short4*)&Alo[(16*r4 + m)*136 + col] = lo4;
        }
    bar_lgkm();

    if (TAIL == 0) {
#pragma unroll
        for (int sec = 0; sec < 3; ++sec) {
            const short* Wh = WhiN + sec*16384;
            const short* Wl = WloN + sec*16384;
            f32x4 a3[4][2];
#pragma unroll
            for (int r4 = 0; r4 < 4; ++r4)
#pragma unroll
                for (int j = 0; j < 2; ++j) a3[r4][j] = (f32x4){0,0,0,0};
#pragma unroll
            for (int ks = 0; ks < 4; ++ks) {
                bf16x8 wh[2], wl[2];
#pragma unroll
                for (int j = 0; j < 2; ++j) {
                    size_t wi = (size_t)(32*w + 16*j + m)*D_ + 32*ks + 8*qd;
                    wh[j] = *(const bf16x8*)(Wh + wi);
                    wl[j] = *(const bf16x8*)(Wl + wi);
                }
#pragma unroll
                for (int r4 = 0; r4 < 4; ++r4) {
                    bf16x8 ah = *(const bf16x8*)&Ahi[(16*r4 + m)*136 + 32*ks + 8*qd];
                    bf16x8 al = *(const bf16x8*)&Alo[(16*r4 + m)*136 + 32*ks + 8*qd];
#pragma unroll
                    for (int j = 0; j < 2; ++j) {
                        a3[r4][j] = __builtin_amdgcn_mfma_f32_16x16x32_bf16(wh[j], ah, a3[r4][j], 0, 0, 0);
                        a3[r4][j] = __builtin_amdgcn_mfma_f32_16x16x32_bf16(wh[j], al, a3[r4][j], 0, 0, 0);
                        a3[r4][j] = __builtin_amdgcn_mfma_f32_16x16x32_bf16(wl[j], ah, a3[r4][j], 0, 0, 0);
                    }
                }
            }
#pragma unroll
            for (int r4 = 0; r4 < 4; ++r4) {
                int row = row0 + 16*r4 + m;
                int l = row & 2047;
#pragma unroll
                for (int j = 0; j < 2; ++j) {
                    int col = 32*w + 16*j + 4*qd;
                    f32x4 v = a3[r4][j];
                    if (sec == 0) {
                        float4 sv = {v[0], v[1], v[2], v[3]};
                        *(float4*)(qout + (size_t)row*D_ + col) = sv;
                    } else if (sec == 1) {
                        size_t idx = ((size_t)((bb*4 + w)*2048 + l))*32 + (col & 31);
                        short4 hi4, lo4;
                        split2(v[0], hi4.x, lo4.x);
                        split2(v[1], hi4.y, lo4.y);
                        split2(v[2], hi4.z, lo4.z);
                        split2(v[3], hi4.w, lo4.w);
                        *(short4*)(khi + idx) = hi4;
                        *(short4*)(klo + idx) = lo4;
                    } else {
                        size_t basep = (size_t)(bb*4 + w)*32;
#pragma unroll
                        for (int e = 0; e < 4; ++e) {
                            int d = 16*j + 4*qd + e;
                            short hh, ll; split2(v[e], hh, ll);
                            vhiT[(basep + d)*2048 + l] = hh;
                            vloT[(basep + d)*2048 + l] = ll;
                        }
                    }
                }
            }
        }
    } else {
        f32x4 a3[4][2];
#pragma unroll
        for (int r4 = 0; r4 < 4; ++r4)
#pragma unroll
            for (int j = 0; j < 2; ++j) a3[r4][j] = (f32x4){0,0,0,0};
#pragma unroll
        for (int ks = 0; ks < 4; ++ks) {
            bf16x8 wh[2], wl[2];
#pragma unroll
            for (int j = 0; j < 2; ++j) {
                size_t wi = (size_t)(32*w + 16*j + m)*D_ + 32*ks + 8*qd;
                wh[j] = *(const bf16x8*)(WhiN + wi);
                wl[j] = *(const bf16x8*)(WloN + wi);
            }
#pragma unroll
            for (int r4 = 0; r4 < 4; ++r4) {
                bf16x8 ah = *(const bf16x8*)&Ahi[(16*r4 + m)*136 + 32*ks + 8*qd];
                bf16x8 al = *(const bf16x8*)&Alo[(16*r4 + m)*136 + 32*ks + 8*qd];
#pragma unroll
                for (int j = 0; j < 2; ++j) {
                    a3[r4][j] = __builtin_amdgcn_mfma_f32_16x16x32_bf16(wh[j], ah, a3[r4][j], 0, 0, 0);
                    a3[r4][j] = __builtin_amdgcn_mfma_f32_16x16x32_bf16(wh[j], al, a3[r4][j], 0, 0, 0);
                    a3[r4][j] = __builtin_amdgcn_mfma_f32_16x16x32_bf16(wl[j], ah, a3[r4][j], 0, 0, 0);
                }
            }
        }
#pragma unroll
        for (int r4 = 0; r4 < 4; ++r4) {
            float dotp = 0.0f;
#pragma unroll
            for (int j = 0; j < 2; ++j) {
                int col = 32*w + 16*j + 4*qd;
                f32x4 v = a3[r4][j];
                float4 bv = *(const float4*)(bfv + col);
                v[0] += bv.x; v[1] += bv.y; v[2] += bv.z; v[3] += bv.w;
#pragma unroll
                for (int e = 0; e < 4; ++e) v[e] = tanhf(v[e]);
                float4 uv = *(const float4*)(uf + col);
                dotp += v[0]*uv.x + v[1]*uv.y + v[2]*uv.z + v[3]*uv.w;
            }
            part[16*r4 + m][4*w + qd] = dotp;
        }
        __syncthreads();
        if (t < 64) {
            float s = 0.0f;
#pragma unroll
            for (int i = 0; i < 16; ++i) s += part[t][i];
            attb[row0 + t] = s + cfm[row0 + t];
        }
    }
}

// ---------------------------------------------------------------------------
// Pooling
// ---------------------------------------------------------------------------
__global__ __launch_bounds__(256)
void pool_stats_kernel(const float* __restrict__ att, const int* __restrict__ kcount,
                       float* __restrict__ p)
{
    int b = blockIdx.x, t = threadIdx.x;
    int lim = (kcount[b] + 63) & ~63;
    __shared__ float red[4];
    __shared__ float a_s[L_];

    float m = -INFINITY;
    for (int l = t; l < L_; l += 256) {
        float a = (l < lim) ? att[b*L_ + l] : FMINV;
        a_s[l] = a;
        m = fmaxf(m, a);
    }
#pragma unroll
    for (int s = 1; s < 64; s <<= 1) m = fmaxf(m, __shfl_xor(m, s));
    if ((t & 63) == 0) red[t >> 6] = m;
    __syncthreads();
    m = fmaxf(fmaxf(red[0], red[1]), fmaxf(red[2], red[3]));
    __syncthreads();

    float s = 0.0f;
    for (int l = t; l < L_; l += 256) s += __expf(a_s[l] - m);
#pragma unroll
    for (int st = 1; st < 64; st <<= 1) s += __shfl_xor(s, st);
    if ((t & 63) == 0) red[t >> 6] = s;
    __syncthreads();
    s = red[0] + red[1] + red[2] + red[3];
    float inv = 1.0f / s;
    for (int l = t; l < L_; l += 256)
        p[b*L_ + l] = (l < lim) ? __expf(a_s[l] - m) * inv : 0.0f;
}

__global__ __launch_bounds__(128)
void pool_partial_kernel(const float* __restrict__ p, const float* __restrict__ x,
                         float* __restrict__ part)
{
    int c = blockIdx.x, b = blockIdx.y, d = threadIdx.x;
    const float* xb = x + ((size_t)(b*L_ + c*128))*D_ + d;
    const float* pb = p + b*L_ + c*128;
    float acc = 0.0f;
#pragma unroll 4
    for (int i = 0; i < 128; ++i) acc += pb[i] * xb[(size_t)i*D_];
    part[((size_t)b*16 + c)*D_ + d] = acc;
}

// ---------------------------------------------------------------------------
// Head (+inline demographics MLP for row b)
// ---------------------------------------------------------------------------
__global__ __launch_bounds__(256)
void head_kernel(const float* __restrict__ part, const float* __restrict__ demog,
                 const float* __restrict__ Wd1, const float* __restrict__ bd1,
                 const float* __restrict__ Wd2, const float* __restrict__ bd2,
                 const float* __restrict__ Wh, const float* __restrict__ bh,
                 float* __restrict__ out)
{
    int b = blockIdx.x, t = threadIdx.x;
    __shared__ float tss[128];
    __shared__ float hs1[256];
    __shared__ float dems[128];
    if (t < 128) {
        float s = 0.0f;
#pragma unroll
        for (int c = 0; c < 16; ++c) s += part[((size_t)b*16 + c)*D_ + t];
        tss[t] = s;
    }
    {
        float a = bd1[t];
#pragma unroll
        for (int kk = 0; kk < DM_; ++kk) a += demog[b*DM_ + kk] * Wd1[kk*(2*D_) + t];
        hs1[t] = tanhf(a);
    }
    __syncthreads();
    if (t < 128) {
        float a = bd2[t];
        for (int kk = 0; kk < 2*D_; ++kk) a += hs1[kk] * Wd2[kk*D_ + t];
        dems[t] = a;
    }
    __syncthreads();
    if (t >= F_OUT) return;
    float acc = bh[t];
    for (int k2 = 0; k2 < D_; ++k2) acc += tss[k2]  * Wh[k2*F_OUT + t];
    for (int k2 = 0; k2 < D_; ++k2) acc += dems[k2] * Wh[(D_+k2)*F_OUT + t];
    out[b*F_OUT + t] = acc;
}

// ---------------------------------------------------------------------------
extern "C" void kernel_launch(void* const* d_in, const int* in_sizes, int n_in,
                              void* d_out, int out_size, void* d_ws, size_t ws_size,
                              hipStream_t stream)
{
    (void)in_sizes; (void)n_in; (void)out_size; (void)ws_size;
    const float* values       = (const float*)d_in[0];
    const float* times        = (const float*)d_in[1];
    const int*   variables    = (const int*)  d_in[2];
    const int*   input_mask   = (const int*)  d_in[3];
    const float* demographics = (const float*)d_in[4];
    const float* W1t = (const float*)d_in[5];
    const float* b1t = (const float*)d_in[6];
    const float* W2t = (const float*)d_in[7];
    const float* W1v = (const float*)d_in[8];
    const float* b1v = (const float*)d_in[9];
    const float* W2v = (const float*)d_in[10];
    const float* var_table = (const float*)d_in[11];
    const float* Wq  = (const float*)d_in[12];
    const float* Wk  = (const float*)d_in[13];
    const float* Wv  = (const float*)d_in[14];
    const float* Wo  = (const float*)d_in[15];
    const float* W1  = (const float*)d_in[16];
    const float* b1  = (const float*)d_in[17];
    const float* W2  = (const float*)d_in[18];
    const float* b2  = (const float*)d_in[19];
    const float* Wf  = (const float*)d_in[20];
    const float* bfv = (const float*)d_in[21];
    const float* uf  = (const float*)d_in[22];
    const float* Wd1 = (const float*)d_in[23];
    const float* bd1 = (const float*)d_in[24];
    const float* Wd2 = (const float*)d_in[25];
    const float* bd2 = (const float*)d_in[26];
    const float* Wh  = (const float*)d_in[27];
    const float* bhv = (const float*)d_in[28];
    float* out = (float*)d_out;

    float* ws     = (float*)d_ws;
    float* x      = ws;                   // compact rows
    float* qb     = ws + (size_t)SZ_X;
    float* region = ws + (size_t)2*SZ_X;
    short* khi    = (short*)region;
    short* klo    = khi + (size_t)SZ_X;
    short* vhiT   = klo + (size_t)SZ_X;
    short* vloT   = vhiT + (size_t)SZ_X;
    float* attb   = ws + (size_t)4*SZ_X;  // BL_
    float* attp   = attb + BL_;           // BL_
    float* partb  = attp + BL_;           // B_*16*D_
    short* wt_hi  = (short*)(partb + B_*16*D_);  // NL_*WT_TOT + 16384 shorts
    short* wt_lo  = wt_hi + ((size_t)NL_*WT_TOT + 16384);
    int*   posb   = (int*)(wt_lo + ((size_t)NL_*WT_TOT + 16384));
    int*   kcountb= posb + BL_;
    float* cfmb   = (float*)(kcountb + B_ + 3);
    float* opart  = cfmb + BL_;                  // 2*SZ_X
    float* mlm    = opart + (size_t)2*SZ_X;      // B_*H_*2*2048
    float* mll    = mlm + (size_t)B_*H_*2*2048;
    short* wfhi   = wt_hi + (size_t)NL_*WT_TOT;
    short* wflo   = wt_lo + (size_t)NL_*WT_TOT;

    compact_kernel<<<B_, 256, 0, stream>>>(input_mask, posb, kcountb, cfmb, x);
    embed_kernel<<<BL_, 128, 0, stream>>>(values, times, variables, posb,
                                          W1t, b1t, W2t, W1v, b1v, W2v,
                                          var_table, x);
    split_all_kernel<<<(NL_*131072 + 16384)/256, 256, 0, stream>>>(
        Wq, Wk, Wv, Wo, W1, W2, Wf, wt_hi, wt_lo);

    gemm_qkv_fused<<<dim3(BL_/64, 3), 256, 0, stream>>>(x,
        wt_hi + 0*WT_TOT, wt_lo + 0*WT_TOT, kcountb, qb, khi, klo, vhiT, vloT);

    for (int i = 0; i < NL_; ++i) {
        short* whL = wt_hi + (size_t)i*WT_TOT;
        short* wlL = wt_lo + (size_t)i*WT_TOT;
        attn_mfma_kernel<<<dim3(L_/64, H_*2, B_), 256, 0, stream>>>(qb, khi, klo,
            vhiT, vloT, kcountb, cfmb, opart, mlm, mll);
        if (i < NL_ - 1) {
            short* whN = wt_hi + (size_t)(i+1)*WT_TOT;
            short* wlN = wt_lo + (size_t)(i+1)*WT_TOT;
            layer_fused_kernel<0><<<BL_/64, 256, 0, stream>>>(opart, mlm, mll,
                whL+WT_O, wlL+WT_O, whL+WT_1, wlL+WT_1, b1 + i*DFF_,
                whL+WT_2, wlL+WT_2, b2 + i*D_, whN, wlN,
                nullptr, nullptr, nullptr, kcountb, x,
                qb, khi, klo, vhiT, vloT, nullptr);
        } else {
            layer_fused_kernel<1><<<BL_/64, 256, 0, stream>>>(opart, mlm, mll,
                whL+WT_O, wlL+WT_O, whL+WT_1, wlL+WT_1, b1 + i*DFF_,
                whL+WT_2, wlL+WT_2, b2 + i*D_, wfhi, wflo,
                bfv, uf, cfmb, kcountb, x,
                nullptr, nullptr, nullptr, nullptr, nullptr, attb);
        }
    }

    pool_stats_kernel<<<B_, 256, 0, stream>>>(attb, kcountb, attp);
    pool_partial_kernel<<<dim3(16, B_), 128, 0, stream>>>(attp, x, partb);
    head_kernel<<<B_, 256, 0, stream>>>(partb, demographics, Wd1, bd1, Wd2, bd2,
                                        Wh, bhv, out);
}

// Round 7
// 794.996 us; speedup vs baseline: 1.0105x; 1.0105x over previous
//
#include <hip/hip_runtime.h>
#include <hip/hip_bf16.h>
#include <math.h>

#define B_   16
#define L_   2048
#define D_   128
#define H_   4
#define NL_  4
#define DK_  32
#define DFF_ 256
#define INTD_ 11
#define F_OUT 129
#define DM_  16
#define FMINV (-3.402823466e38f)
#define LOG2E 1.4426950408889634f

#define BL_  (B_*L_)      // 32768
#define SZ_X (BL_*D_)     // 4194304 floats

#define WT_Q 0
#define WT_K 16384
#define WT_V 32768
#define WT_O 49152
#define WT_1 65536
#define WT_2 98304
#define WT_TOT 131072

typedef __attribute__((ext_vector_type(8))) short bf16x8;
typedef __attribute__((ext_vector_type(4))) float f32x4;

#if __has_builtin(__builtin_amdgcn_exp2f)
#define EXP2F(x) __builtin_amdgcn_exp2f(x)
#else
#define EXP2F(x) __expf(0.69314718055994531f*(x))
#endif

static __device__ __forceinline__ short f2bf(float x) {
    union { __hip_bfloat16 h; short s; } u;
    u.h = __float2bfloat16(x);
    return u.s;
}
static __device__ __forceinline__ float bf2f(short s) {
    union { __hip_bfloat16 h; short t; } u;
    u.t = s;
    return __bfloat162float(u.h);
}
static __device__ __forceinline__ void split2(float v, short& h, short& l) {
    h = f2bf(v); l = f2bf(v - bf2f(h));
}
static __device__ __forceinline__ void split_trunc(float v, short& h, short& l) {
    unsigned u = __float_as_uint(v);
    h = (short)(u >> 16);
    float r = v - __uint_as_float(u & 0xffff0000u);
    l = (short)(__float_as_uint(r) >> 16);
}
// Raw workgroup barrier draining LDS only: outstanding GLOBAL loads/stores
// stay in flight (compiler's __syncthreads would emit vmcnt(0) too).
static __device__ __forceinline__ void bar_lgkm() {
    asm volatile("s_waitcnt lgkmcnt(0)" ::: "memory");
    __builtin_amdgcn_s_barrier();
}

// ---------------------------------------------------------------------------
// Mask compaction + x tail-zero: pos, kcount, cfm; zeroes x rows [Kb,ceil64).
// ---------------------------------------------------------------------------
__global__ __launch_bounds__(256)
void compact_kernel(const int* __restrict__ mask, int* __restrict__ pos,
                    int* __restrict__ kcount, float* __restrict__ cfm,
                    float* __restrict__ x)
{
    int b = blockIdx.x, t = threadIdx.x;
    int lane = t & 63, w = t >> 6;
    __shared__ int wsum[4];
    __shared__ int tot_s;
    int mv[8], loc[8], s = 0;
#pragma unroll
    for (int i = 0; i < 8; ++i) {
        mv[i] = mask[b*L_ + t*8 + i];
        loc[i] = s;
        s += mv[i];
    }
    int v = s;
#pragma unroll
    for (int d = 1; d < 64; d <<= 1) {
        int y = __shfl_up(v, d);
        if (lane >= d) v += y;
    }
    int excl = v - s;
    if (lane == 63) wsum[w] = v;
    __syncthreads();
    int wbase = 0;
    for (int i = 0; i < w; ++i) wbase += wsum[i];
    int base = wbase + excl;
#pragma unroll
    for (int i = 0; i < 8; ++i)
        pos[b*L_ + t*8 + i] = mv[i] ? (base + loc[i]) : -1;
    if (t == 255) { kcount[b] = base + s; tot_s = base + s; }
    __syncthreads();
    int tot = tot_s;
    for (int l = t; l < L_; l += 256) cfm[b*L_ + l] = (l < tot) ? 0.0f : FMINV;
    int end = (tot + 63) & ~63;
    int nz = (end - tot) * D_;
    for (int i = t; i < nz; i += 256)
        x[((size_t)(b*2048 + tot))*D_ + i] = 0.0f;
}

// ---------------------------------------------------------------------------
// Embedding with compaction
// ---------------------------------------------------------------------------
__global__ __launch_bounds__(128)
void embed_kernel(const float* __restrict__ values, const float* __restrict__ times,
                  const int* __restrict__ variables, const int* __restrict__ pos,
                  const float* __restrict__ W1t, const float* __restrict__ b1t,
                  const float* __restrict__ W2t,
                  const float* __restrict__ W1v, const float* __restrict__ b1v,
                  const float* __restrict__ W2v,
                  const float* __restrict__ var_table, float* __restrict__ x)
{
    int bl = blockIdx.x;
    int p  = pos[bl];
    if (p < 0) return;
    int t  = threadIdx.x;
    __shared__ float th[INTD_], vh[INTD_];
    if (t < INTD_)                th[t]    = tanhf(times[bl]  * W1t[t]    + b1t[t]);
    if (t >= 64 && t < 64+INTD_)  vh[t-64] = tanhf(values[bl] * W1v[t-64] + b1v[t-64]);
    __syncthreads();
    int var = variables[bl];
    float acc = var_table[var*D_ + t];
#pragma unroll
    for (int i = 0; i < INTD_; ++i)
        acc += th[i]*W2t[i*D_ + t] + vh[i]*W2v[i*D_ + t];
    x[((size_t)((bl >> 11)*2048 + p))*D_ + t] = acc;
}

// ---------------------------------------------------------------------------
// Weight pre-split: all 4 layers + Wf appended at offset NL_*WT_TOT.
// ---------------------------------------------------------------------------
__global__ __launch_bounds__(256)
void split_all_kernel(const float* __restrict__ Wq, const float* __restrict__ Wk,
                      const float* __restrict__ Wv, const float* __restrict__ Wo,
                      const float* __restrict__ W1, const float* __restrict__ W2,
                      const float* __restrict__ Wf,
                      short* __restrict__ hi, short* __restrict__ lo)
{
    int gidx = blockIdx.x*256 + threadIdx.x;
    float v;
    if (gidx < NL_*131072) {
        int layer = gidx >> 17;
        int idx   = gidx & 131071;
        if (idx < 49152) {
            int which = idx >> 14;
            int r = idx & 16383;
            int col = r >> 7, k = r & 127;
            int h = col >> 5, e = col & 31;
            const float* src = ((which == 0) ? Wq : (which == 1) ? Wk : Wv)
                               + (size_t)layer*H_*D_*DK_;
            v = src[(h*D_ + k)*DK_ + e];
        } else if (idx < 65536) {
            int r = idx - 49152;
            int col = r >> 7, k = r & 127;
            v = Wo[(size_t)layer*D_*D_ + k*D_ + col];
        } else if (idx < 98304) {
            int r = idx - 65536;
            int col = r >> 7, k = r & 127;
            v = W1[(size_t)layer*D_*DFF_ + k*DFF_ + col];
        } else {
            int r = idx - 98304;
            int col = r >> 8, k = r & 255;
            v = W2[(size_t)layer*DFF_*D_ + k*D_ + col];
        }
    } else {
        int r = gidx - NL_*131072;      // Wf: 16384 elems, [col][K]
        int col = r >> 7, k = r & 127;
        v = Wf[k*D_ + col];
    }
    short h2, l2; split2(v, h2, l2);
    hi[gidx] = h2; lo[gidx] = l2;
}

// ---------------------------------------------------------------------------
// Fused QKV GEMM (layer 0 only), one weight stream per block (grid.y=3).
// ---------------------------------------------------------------------------
__global__ __launch_bounds__(256)
void gemm_qkv_fused(const float* __restrict__ A, const short* __restrict__ Whi,
                    const short* __restrict__ Wlo, const int* __restrict__ kcount,
                    float* __restrict__ qout,
                    short* __restrict__ khi, short* __restrict__ klo,
                    short* __restrict__ vhiT, short* __restrict__ vloT)
{
    const int row0 = blockIdx.x * 64;
    const int bb = row0 >> 11;
    if ((row0 & 2047) >= ((kcount[bb] + 63) & ~63)) return;
    const int sec = blockIdx.y;

    __shared__ short Ahi[64*136];
    __shared__ short Alo[64*136];
    const int t = threadIdx.x;
    const int w = t >> 6, lane = t & 63;
    const int m = lane & 15, qd = lane >> 4;

#pragma unroll
    for (int i = 0; i < 8; ++i) {
        int r = (t >> 5) + 8*i;
        int c = (t & 31) * 4;
        float4 av = *(const float4*)(A + (size_t)(row0 + r)*D_ + c);
        short4 hi4, lo4;
        split2(av.x, hi4.x, lo4.x);
        split2(av.y, hi4.y, lo4.y);
        split2(av.z, hi4.z, lo4.z);
        split2(av.w, hi4.w, lo4.w);
        *(short4*)&Ahi[r*136 + c] = hi4;
        *(short4*)&Alo[r*136 + c] = lo4;
    }
    __syncthreads();

    const short* Wh = Whi + sec*16384;
    const short* Wl = Wlo + sec*16384;
    f32x4 acc[4][2];
#pragma unroll
    for (int r4 = 0; r4 < 4; ++r4)
#pragma unroll
        for (int j = 0; j < 2; ++j) acc[r4][j] = (f32x4){0,0,0,0};

#pragma unroll
    for (int ks = 0; ks < 4; ++ks) {
        bf16x8 wh[2], wl[2];
#pragma unroll
        for (int j = 0; j < 2; ++j) {
            size_t wi = (size_t)(32*w + 16*j + m)*D_ + 32*ks + 8*qd;
            wh[j] = *(const bf16x8*)(Wh + wi);
            wl[j] = *(const bf16x8*)(Wl + wi);
        }
#pragma unroll
        for (int r4 = 0; r4 < 4; ++r4) {
            bf16x8 ah = *(const bf16x8*)&Ahi[(16*r4 + m)*136 + 32*ks + 8*qd];
            bf16x8 al = *(const bf16x8*)&Alo[(16*r4 + m)*136 + 32*ks + 8*qd];
#pragma unroll
            for (int j = 0; j < 2; ++j) {
                acc[r4][j] = __builtin_amdgcn_mfma_f32_16x16x32_bf16(wh[j], ah, acc[r4][j], 0, 0, 0);
                acc[r4][j] = __builtin_amdgcn_mfma_f32_16x16x32_bf16(wh[j], al, acc[r4][j], 0, 0, 0);
                acc[r4][j] = __builtin_amdgcn_mfma_f32_16x16x32_bf16(wl[j], ah, acc[r4][j], 0, 0, 0);
            }
        }
    }

#pragma unroll
    for (int r4 = 0; r4 < 4; ++r4) {
        int row = row0 + 16*r4 + m;
        int l = row & 2047;
#pragma unroll
        for (int j = 0; j < 2; ++j) {
            int col = 32*w + 16*j + 4*qd;
            f32x4 v = acc[r4][j];
            if (sec == 0) {
                float4 sv = {v[0], v[1], v[2], v[3]};
                *(float4*)(qout + (size_t)row*D_ + col) = sv;
            } else if (sec == 1) {
                size_t idx = ((size_t)((bb*4 + w)*2048 + l))*32 + (col & 31);
                short4 hi4, lo4;
                split2(v[0], hi4.x, lo4.x);
                split2(v[1], hi4.y, lo4.y);
                split2(v[2], hi4.z, lo4.z);
                split2(v[3], hi4.w, lo4.w);
                *(short4*)(khi + idx) = hi4;
                *(short4*)(klo + idx) = lo4;
            } else {
                size_t basep = (size_t)(bb*4 + w)*32;
#pragma unroll
                for (int e = 0; e < 4; ++e) {
                    int d = 16*j + 4*qd + e;
                    short hh, ll; split2(v[e], hh, ll);
                    vhiT[(basep + d)*2048 + l] = hh;
                    vloT[(basep + d)*2048 + l] = ll;
                }
            }
        }
    }
}

// ---------------------------------------------------------------------------
// SPLIT-K MFMA flash attention — R7: TWO q-tiles per block (qtp*2, qtp*2+1)
// against the same K/V staging. Halves staging traffic, barriers, and K
// ds_reads per unit compute; gives each wave two independent dep chains
// (softmax-A overlaps QK/PV-B in the scheduler). Boundary-invalid tile B is
// computed-and-discarded (uniform; aliases tile A). Keeps R3's dbuf +
// single lgkm-only barrier per tile (best-measured). LDS 40960 B.
// ---------------------------------------------------------------------------
__global__ __launch_bounds__(256)
void attn_mfma_kernel(const float* __restrict__ q,
                      const short* __restrict__ khi, const short* __restrict__ klo,
                      const short* __restrict__ vhiT, const short* __restrict__ vloT,
                      const int* __restrict__ kcount, const float* __restrict__ cfm,
                      float* __restrict__ opart, float* __restrict__ mlm,
                      float* __restrict__ mll)
{
    (void)cfm;
    __shared__ short KhiS[2][2048];   // [buf][key*32 + dim]   rows 64B, aligned
    __shared__ short KloS[2][2048];
    __shared__ short Vthi[2][2048];   // [buf][d*64 + swz-chunk] rows 128B
    __shared__ short Vtlo[2][2048];
    __shared__ short Ps[4][1024];     // per-wave [m*64 + swz-chunk]; reused A/B

    const int t    = threadIdx.x;
    const int w    = t >> 6;
    const int lane = t & 63;
    const int m    = lane & 15;
    const int qd   = lane >> 4;
    const int qtp = blockIdx.x, b = blockIdx.z;
    const int h = blockIdx.y & 3, half = blockIdx.y >> 2;

    const int Kb = kcount[b];
    const int qtA = qtp*2;
    if (qtA*64 >= Kb) return;
    const bool validB = ((qtA+1)*64 < Kb);
    const int qtB = validB ? (qtA+1) : qtA;

    const int nt = (Kb + 63) >> 6;
    const int ntH = (nt + 1) >> 1;
    const int kt0 = half * ntH;
    const int kt1 = (kt0 + ntH < nt) ? (kt0 + ntH) : nt;
    const size_t mlbase = (((size_t)(b*4 + h))*2 + half)*2048;

    if (kt0 >= kt1) {
        if (lane < 16) {
            mlm[mlbase + qtA*64 + 16*w + lane] = FMINV;
            mll[mlbase + qtA*64 + 16*w + lane] = 0.0f;
            if (validB) {
                mlm[mlbase + qtB*64 + 16*w + lane] = FMINV;
                mll[mlbase + qtB*64 + 16*w + lane] = 0.0f;
            }
        }
        return;
    }

    const size_t hd = ((size_t)(b*4 + h))*2048*32;
    const int vd = t >> 3;
    const int vk = t & 7;
    const size_t vbase = ((size_t)(b*4 + h)*32 + vd)*2048 + vk*8;
    const int vw_off = vd*64 + ((vk ^ (vd & 7)) << 3);   // swizzled V slot

    // Q fragments for both q-tiles
    bf16x8 qhiA, qloA, qhiB, qloB;
    {
        const float* qpA = q + ((size_t)(b*L_ + qtA*64 + 16*w + m))*D_ + h*DK_ + 8*qd;
        const float* qpB = q + ((size_t)(b*L_ + qtB*64 + 16*w + m))*D_ + h*DK_ + 8*qd;
        float qfA[8], qfB[8];
        *(float4*)&qfA[0] = *(const float4*)qpA;
        *(float4*)&qfA[4] = *(const float4*)(qpA + 4);
        *(float4*)&qfB[0] = *(const float4*)qpB;
        *(float4*)&qfB[4] = *(const float4*)(qpB + 4);
#pragma unroll
        for (int j = 0; j < 8; ++j) {
            float qsA = qfA[j] * LOG2E;
            short hsA = f2bf(qsA);
            qhiA[j] = hsA;
            qloA[j] = f2bf(qsA - bf2f(hsA));
            float qsB = qfB[j] * LOG2E;
            short hsB = f2bf(qsB);
            qhiB[j] = hsB;
            qloB[j] = f2bf(qsB - bf2f(hsB));
        }
    }

    bf16x8 pkh, pkl, pvh, pvl;
    {
        const size_t gk = hd + (size_t)kt0*64*32 + t*8;
        pkh = *(const bf16x8*)(khi + gk);
        pkl = *(const bf16x8*)(klo + gk);
        pvh = *(const bf16x8*)(vhiT + vbase + (size_t)kt0*64);
        pvl = *(const bf16x8*)(vloT + vbase + (size_t)kt0*64);
    }

    float m_oldA = -INFINITY, l_runA = 0.0f;
    float m_oldB = -INFINITY, l_runB = 0.0f;
    f32x4 oA[2] = {{0,0,0,0},{0,0,0,0}};
    f32x4 oB[2] = {{0,0,0,0},{0,0,0,0}};

    for (int kt = kt0; kt < kt1; ++kt) {
        const int buf = kt & 1;
        // ---- stage current tile into LDS[buf] ----
        *(bf16x8*)&KhiS[buf][t*8] = pkh;
        *(bf16x8*)&KloS[buf][t*8] = pkl;
        *(bf16x8*)&Vthi[buf][vw_off] = pvh;
        *(bf16x8*)&Vtlo[buf][vw_off] = pvl;
        // ---- issue next-tile prefetch; stays in flight across the barrier ----
        if (kt + 1 < kt1) {
            const size_t gk = hd + (size_t)(kt+1)*64*32 + t*8;
            pkh = *(const bf16x8*)(khi + gk);
            pkl = *(const bf16x8*)(klo + gk);
            pvh = *(const bf16x8*)(vhiT + vbase + (size_t)(kt+1)*64);
            pvl = *(const bf16x8*)(vloT + vbase + (size_t)(kt+1)*64);
        }
        // ---- single barrier: drain LDS only (NOT vmcnt) ----
        bar_lgkm();
        __builtin_amdgcn_sched_barrier(0);

        // ---- QK^T for both tiles; K fragments loaded ONCE ----
        f32x4 sfA[4], sfB[4];
#pragma unroll
        for (int k4 = 0; k4 < 4; ++k4) {
            bf16x8 ka = *(const bf16x8*)&KhiS[buf][(16*k4 + m)*32 + 8*qd];
            bf16x8 kl = *(const bf16x8*)&KloS[buf][(16*k4 + m)*32 + 8*qd];
            f32x4 cA = {0,0,0,0};
            cA = __builtin_amdgcn_mfma_f32_16x16x32_bf16(ka, qhiA, cA, 0, 0, 0);
            cA = __builtin_amdgcn_mfma_f32_16x16x32_bf16(ka, qloA, cA, 0, 0, 0);
            cA = __builtin_amdgcn_mfma_f32_16x16x32_bf16(kl, qhiA, cA, 0, 0, 0);
            sfA[k4] = cA;
            f32x4 cB = {0,0,0,0};
            cB = __builtin_amdgcn_mfma_f32_16x16x32_bf16(ka, qhiB, cB, 0, 0, 0);
            cB = __builtin_amdgcn_mfma_f32_16x16x32_bf16(ka, qloB, cB, 0, 0, 0);
            cB = __builtin_amdgcn_mfma_f32_16x16x32_bf16(kl, qhiB, cB, 0, 0, 0);
            sfB[k4] = cB;
        }

        // ---- mask (k-column based: identical for A and B) ----
        float svA[16], svB[16];
        if (kt == nt - 1) {
            const int rel = Kb - kt*64;
#pragma unroll
            for (int k4 = 0; k4 < 4; ++k4)
#pragma unroll
                for (int e = 0; e < 4; ++e) {
                    float msk = ((16*k4 + 4*qd + e) < rel) ? 0.0f : FMINV;
                    svA[4*k4+e] = sfA[k4][e] + msk;
                    svB[4*k4+e] = sfB[k4][e] + msk;
                }
        } else {
#pragma unroll
            for (int k4 = 0; k4 < 4; ++k4)
#pragma unroll
                for (int e = 0; e < 4; ++e) {
                    svA[4*k4+e] = sfA[k4][e];
                    svB[4*k4+e] = sfB[k4][e];
                }
        }

        // ---- softmax A ----
        float alphaA;
        short pbhA[16], pblA[16];
        {
            float mx8[8];
#pragma unroll
            for (int j = 0; j < 8; ++j) mx8[j] = fmaxf(svA[2*j], svA[2*j+1]);
#pragma unroll
            for (int j = 0; j < 4; ++j) mx8[j] = fmaxf(mx8[j], mx8[j+4]);
            float tmax = fmaxf(fmaxf(mx8[0], mx8[1]), fmaxf(mx8[2], mx8[3]));
            tmax = fmaxf(tmax, __shfl_xor(tmax, 16));
            tmax = fmaxf(tmax, __shfl_xor(tmax, 32));
            float mnew  = fmaxf(m_oldA, tmax);
            alphaA = EXP2F(m_oldA - mnew);
            float pj[16];
#pragma unroll
            for (int j = 0; j < 16; ++j) {
                float p = EXP2F(svA[j] - mnew);
                pj[j] = p;
                split_trunc(p, pbhA[j], pblA[j]);
            }
            float ps8[8];
#pragma unroll
            for (int j = 0; j < 8; ++j) ps8[j] = pj[2*j] + pj[2*j+1];
#pragma unroll
            for (int j = 0; j < 4; ++j) ps8[j] = ps8[j] + ps8[j+4];
            float psum = (ps8[0] + ps8[1]) + (ps8[2] + ps8[3]);
            psum += __shfl_xor(psum, 16);
            psum += __shfl_xor(psum, 32);
            l_runA = l_runA * alphaA + psum;
            m_oldA = mnew;
        }
        // ---- softmax B ----
        float alphaB;
        short pbhB[16], pblB[16];
        {
            float mx8[8];
#pragma unroll
            for (int j = 0; j < 8; ++j) mx8[j] = fmaxf(svB[2*j], svB[2*j+1]);
#pragma unroll
            for (int j = 0; j < 4; ++j) mx8[j] = fmaxf(mx8[j], mx8[j+4]);
            float tmax = fmaxf(fmaxf(mx8[0], mx8[1]), fmaxf(mx8[2], mx8[3]));
            tmax = fmaxf(tmax, __shfl_xor(tmax, 16));
            tmax = fmaxf(tmax, __shfl_xor(tmax, 32));
            float mnew  = fmaxf(m_oldB, tmax);
            alphaB = EXP2F(m_oldB - mnew);
            float pj[16];
#pragma unroll
            for (int j = 0; j < 16; ++j) {
                float p = EXP2F(svB[j] - mnew);
                pj[j] = p;
                split_trunc(p, pbhB[j], pblB[j]);
            }
            float ps8[8];
#pragma unroll
            for (int j = 0; j < 8; ++j) ps8[j] = pj[2*j] + pj[2*j+1];
#pragma unroll
            for (int j = 0; j < 4; ++j) ps8[j] = ps8[j] + ps8[j+4];
            float psum = (ps8[0] + ps8[1]) + (ps8[2] + ps8[3]);
            psum += __shfl_xor(psum, 16);
            psum += __shfl_xor(psum, 32);
            l_runB = l_runB * alphaB + psum;
            m_oldB = mnew;
        }

        // ---- P/PV tile A (Ps is wave-private, in-order DS => safe reuse) ----
#pragma unroll
        for (int k4 = 0; k4 < 4; ++k4) {
            short4 s4h;
            s4h.x = pbhA[4*k4+0]; s4h.y = pbhA[4*k4+1]; s4h.z = pbhA[4*k4+2]; s4h.w = pbhA[4*k4+3];
            int chunk = 2*k4 + (qd >> 1);
            int po = m*64 + ((chunk ^ (m & 7)) << 3) + ((qd & 1) << 2);
            *(short4*)&Ps[w][po] = s4h;
        }
        {
            float a0 = __shfl(alphaA, 4*qd + 0);
            float a1 = __shfl(alphaA, 4*qd + 1);
            float a2 = __shfl(alphaA, 4*qd + 2);
            float a3 = __shfl(alphaA, 4*qd + 3);
            oA[0][0]*=a0; oA[0][1]*=a1; oA[0][2]*=a2; oA[0][3]*=a3;
            oA[1][0]*=a0; oA[1][1]*=a1; oA[1][2]*=a2; oA[1][3]*=a3;
        }
#pragma unroll
        for (int s = 0; s < 2; ++s) {
#pragma unroll
            for (int tp = 0; tp < 2; ++tp) {
                bf16x8 pah = *(const bf16x8*)&Ps[w][m*64 + (((4*s + qd) ^ (m & 7)) << 3)];
                int vr = (16*tp + m)*64 + (((4*s + qd) ^ (m & 7)) << 3);
                bf16x8 vh = *(const bf16x8*)&Vthi[buf][vr];
                bf16x8 vl = *(const bf16x8*)&Vtlo[buf][vr];
                oA[tp] = __builtin_amdgcn_mfma_f32_16x16x32_bf16(pah, vh, oA[tp], 0, 0, 0);
                oA[tp] = __builtin_amdgcn_mfma_f32_16x16x32_bf16(pah, vl, oA[tp], 0, 0, 0);
            }
        }
#pragma unroll
        for (int k4 = 0; k4 < 4; ++k4) {
            short4 s4l;
            s4l.x = pblA[4*k4+0]; s4l.y = pblA[4*k4+1]; s4l.z = pblA[4*k4+2]; s4l.w = pblA[4*k4+3];
            int chunk = 2*k4 + (qd >> 1);
            int po = m*64 + ((chunk ^ (m & 7)) << 3) + ((qd & 1) << 2);
            *(short4*)&Ps[w][po] = s4l;
        }
#pragma unroll
        for (int s = 0; s < 2; ++s) {
#pragma unroll
            for (int tp = 0; tp < 2; ++tp) {
                bf16x8 pal = *(const bf16x8*)&Ps[w][m*64 + (((4*s + qd) ^ (m & 7)) << 3)];
                int vr = (16*tp + m)*64 + (((4*s + qd) ^ (m & 7)) << 3);
                bf16x8 vh = *(const bf16x8*)&Vthi[buf][vr];
                oA[tp] = __builtin_amdgcn_mfma_f32_16x16x32_bf16(pal, vh, oA[tp], 0, 0, 0);
            }
        }

        // ---- P/PV tile B ----
#pragma unroll
        for (int k4 = 0; k4 < 4; ++k4) {
            short4 s4h;
            s4h.x = pbhB[4*k4+0]; s4h.y = pbhB[4*k4+1]; s4h.z = pbhB[4*k4+2]; s4h.w = pbhB[4*k4+3];
            int chunk = 2*k4 + (qd >> 1);
            int po = m*64 + ((chunk ^ (m & 7)) << 3) + ((qd & 1) << 2);
            *(short4*)&Ps[w][po] = s4h;
        }
        {
            float a0 = __shfl(alphaB, 4*qd + 0);
            float a1 = __shfl(alphaB, 4*qd + 1);
            float a2 = __shfl(alphaB, 4*qd + 2);
            float a3 = __shfl(alphaB, 4*qd + 3);
            oB[0][0]*=a0; oB[0][1]*=a1; oB[0][2]*=a2; oB[0][3]*=a3;
            oB[1][0]*=a0; oB[1][1]*=a1; oB[1][2]*=a2; oB[1][3]*=a3;
        }
#pragma unroll
        for (int s = 0; s < 2; ++s) {
#pragma unroll
            for (int tp = 0; tp < 2; ++tp) {
                bf16x8 pah = *(const bf16x8*)&Ps[w][m*64 + (((4*s + qd) ^ (m & 7)) << 3)];
                int vr = (16*tp + m)*64 + (((4*s + qd) ^ (m & 7)) << 3);
                bf16x8 vh = *(const bf16x8*)&Vthi[buf][vr];
                bf16x8 vl = *(const bf16x8*)&Vtlo[buf][vr];
                oB[tp] = __builtin_amdgcn_mfma_f32_16x16x32_bf16(pah, vh, oB[tp], 0, 0, 0);
                oB[tp] = __builtin_amdgcn_mfma_f32_16x16x32_bf16(pah, vl, oB[tp], 0, 0, 0);
            }
        }
#pragma unroll
        for (int k4 = 0; k4 < 4; ++k4) {
            short4 s4l;
            s4l.x = pblB[4*k4+0]; s4l.y = pblB[4*k4+1]; s4l.z = pblB[4*k4+2]; s4l.w = pblB[4*k4+3];
            int chunk = 2*k4 + (qd >> 1);
            int po = m*64 + ((chunk ^ (m & 7)) << 3) + ((qd & 1) << 2);
            *(short4*)&Ps[w][po] = s4l;
        }
#pragma unroll
        for (int s = 0; s < 2; ++s) {
#pragma unroll
            for (int tp = 0; tp < 2; ++tp) {
                bf16x8 pal = *(const bf16x8*)&Ps[w][m*64 + (((4*s + qd) ^ (m & 7)) << 3)];
                int vr = (16*tp + m)*64 + (((4*s + qd) ^ (m & 7)) << 3);
                bf16x8 vh = *(const bf16x8*)&Vthi[buf][vr];
                oB[tp] = __builtin_amdgcn_mfma_f32_16x16x32_bf16(pal, vh, oB[tp], 0, 0, 0);
            }
        }
    }

    if (lane < 16) {
        mlm[mlbase + qtA*64 + 16*w + lane] = m_oldA;
        mll[mlbase + qtA*64 + 16*w + lane] = l_runA;
        if (validB) {
            mlm[mlbase + qtB*64 + 16*w + lane] = m_oldB;
            mll[mlbase + qtB*64 + 16*w + lane] = l_runB;
        }
    }
    float* ob = opart + (size_t)half*SZ_X;
#pragma unroll
    for (int tp = 0; tp < 2; ++tp)
#pragma unroll
        for (int r = 0; r < 4; ++r)
            ob[((size_t)(b*L_ + qtA*64 + 16*w + 4*qd + r))*D_ + h*DK_ + 16*tp + m] =
                oA[tp][r];
    if (validB) {
#pragma unroll
        for (int tp = 0; tp < 2; ++tp)
#pragma unroll
            for (int r = 0; r < 4; ++r)
                ob[((size_t)(b*L_ + qtB*64 + 16*w + 4*qd + r))*D_ + h*DK_ + 16*tp + m] =
                    oB[tp][r];
    }
}

// ---------------------------------------------------------------------------
// FUSED: split-K merge + Wo GEMM + resid (writes x) + restage + FFN1 + GELU
// (R3's best-measured version: 64-row tile, __syncthreads.)
// ---------------------------------------------------------------------------
__global__ __launch_bounds__(256)
void wo_ffn1_kernel(const float* __restrict__ opart, const float* __restrict__ mlm,
                    const float* __restrict__ mll,
                    const short* __restrict__ WhiO, const short* __restrict__ WloO,
                    const short* __restrict__ Whi1, const short* __restrict__ Wlo1,
                    const float* __restrict__ b1,
                    const int* __restrict__ kcount, float* __restrict__ x,
                    float* __restrict__ hb)
{
    const int row0 = blockIdx.x * 64;
    const int bb = row0 >> 11;
    if ((row0 & 2047) >= ((kcount[bb] + 63) & ~63)) return;

    __shared__ short Ahi[64*136];
    __shared__ short Alo[64*136];
    const int t = threadIdx.x;
    const int w = t >> 6, lane = t & 63;
    const int m = lane & 15, qd = lane >> 4;

    // ---- stage merged O hi/lo ----
#pragma unroll
    for (int i = 0; i < 8; ++i) {
        int r = (t >> 5) + 8*i;
        int c = (t & 31) * 4;
        int row = row0 + r;
        int l = row & 2047;
        int h = c >> 5;
        size_t i0 = (((size_t)(bb*4 + h))*2 + 0)*2048 + l;
        size_t i1 = i0 + 2048;
        float m0 = mlm[i0], m1 = mlm[i1];
        float l0 = mll[i0], l1 = mll[i1];
        float M  = fmaxf(m0, m1);
        float w0 = EXP2F(m0 - M), w1 = EXP2F(m1 - M);
        float inv = 1.0f / (l0*w0 + l1*w1);
        float s0 = w0 * inv, s1 = w1 * inv;
        float4 o0 = *(const float4*)(opart + (size_t)row*D_ + c);
        float4 o1 = *(const float4*)(opart + (size_t)(BL_ + row)*D_ + c);
        float4 av;
        av.x = s0*o0.x + s1*o1.x;
        av.y = s0*o0.y + s1*o1.y;
        av.z = s0*o0.z + s1*o1.z;
        av.w = s0*o0.w + s1*o1.w;
        short4 hi4, lo4;
        split2(av.x, hi4.x, lo4.x);
        split2(av.y, hi4.y, lo4.y);
        split2(av.z, hi4.z, lo4.z);
        split2(av.w, hi4.w, lo4.w);
        *(short4*)&Ahi[r*136 + c] = hi4;
        *(short4*)&Alo[r*136 + c] = lo4;
    }
    __syncthreads();

    // ---- Wo matmul ----
    f32x4 acc[4][2];
#pragma unroll
    for (int r4 = 0; r4 < 4; ++r4)
#pragma unroll
        for (int j = 0; j < 2; ++j) acc[r4][j] = (f32x4){0,0,0,0};
#pragma unroll
    for (int ks = 0; ks < 4; ++ks) {
        bf16x8 wh[2], wl[2];
#pragma unroll
        for (int j = 0; j < 2; ++j) {
            size_t wi = (size_t)(32*w + 16*j + m)*D_ + 32*ks + 8*qd;
            wh[j] = *(const bf16x8*)(WhiO + wi);
            wl[j] = *(const bf16x8*)(WloO + wi);
        }
#pragma unroll
        for (int r4 = 0; r4 < 4; ++r4) {
            bf16x8 ah = *(const bf16x8*)&Ahi[(16*r4 + m)*136 + 32*ks + 8*qd];
            bf16x8 al = *(const bf16x8*)&Alo[(16*r4 + m)*136 + 32*ks + 8*qd];
#pragma unroll
            for (int j = 0; j < 2; ++j) {
                acc[r4][j] = __builtin_amdgcn_mfma_f32_16x16x32_bf16(wh[j], ah, acc[r4][j], 0, 0, 0);
                acc[r4][j] = __builtin_amdgcn_mfma_f32_16x16x32_bf16(wh[j], al, acc[r4][j], 0, 0, 0);
                acc[r4][j] = __builtin_amdgcn_mfma_f32_16x16x32_bf16(wl[j], ah, acc[r4][j], 0, 0, 0);
            }
        }
    }

    // ---- epilogue: xnew = acc + x; write x; keep in regs ----
#pragma unroll
    for (int r4 = 0; r4 < 4; ++r4) {
        int row = row0 + 16*r4 + m;
#pragma unroll
        for (int j = 0; j < 2; ++j) {
            int col = 32*w + 16*j + 4*qd;
            float4 rv = *(const float4*)(x + (size_t)row*D_ + col);
            acc[r4][j][0] += rv.x; acc[r4][j][1] += rv.y;
            acc[r4][j][2] += rv.z; acc[r4][j][3] += rv.w;
            float4 sv = {acc[r4][j][0], acc[r4][j][1], acc[r4][j][2], acc[r4][j][3]};
            *(float4*)(x + (size_t)row*D_ + col) = sv;
        }
    }
    __syncthreads();

    // ---- restage xnew hi/lo ----
#pragma unroll
    for (int r4 = 0; r4 < 4; ++r4) {
#pragma unroll
        for (int j = 0; j < 2; ++j) {
            int col = 32*w + 16*j + 4*qd;
            short4 hi4, lo4;
            split2(acc[r4][j][0], hi4.x, lo4.x);
            split2(acc[r4][j][1], hi4.y, lo4.y);
            split2(acc[r4][j][2], hi4.z, lo4.z);
            split2(acc[r4][j][3], hi4.w, lo4.w);
            *(short4*)&Ahi[(16*r4 + m)*136 + col] = hi4;
            *(short4*)&Alo[(16*r4 + m)*136 + col] = lo4;
        }
    }
    __syncthreads();

    // ---- FFN1 ----
    f32x4 a2[4][4];
#pragma unroll
    for (int r4 = 0; r4 < 4; ++r4)
#pragma unroll
        for (int jj = 0; jj < 4; ++jj) a2[r4][jj] = (f32x4){0,0,0,0};
#pragma unroll
    for (int ks = 0; ks < 4; ++ks) {
        bf16x8 wh[4], wl[4];
#pragma unroll
        for (int jj = 0; jj < 4; ++jj) {
            size_t wi = (size_t)(64*w + 16*jj + m)*D_ + 32*ks + 8*qd;
            wh[jj] = *(const bf16x8*)(Whi1 + wi);
            wl[jj] = *(const bf16x8*)(Wlo1 + wi);
        }
#pragma unroll
        for (int r4 = 0; r4 < 4; ++r4) {
            bf16x8 ah = *(const bf16x8*)&Ahi[(16*r4 + m)*136 + 32*ks + 8*qd];
            bf16x8 al = *(const bf16x8*)&Alo[(16*r4 + m)*136 + 32*ks + 8*qd];
#pragma unroll
            for (int jj = 0; jj < 4; ++jj) {
                a2[r4][jj] = __builtin_amdgcn_mfma_f32_16x16x32_bf16(wh[jj], ah, a2[r4][jj], 0, 0, 0);
                a2[r4][jj] = __builtin_amdgcn_mfma_f32_16x16x32_bf16(wh[jj], al, a2[r4][jj], 0, 0, 0);
                a2[r4][jj] = __builtin_amdgcn_mfma_f32_16x16x32_bf16(wl[jj], ah, a2[r4][jj], 0, 0, 0);
            }
        }
    }

#pragma unroll
    for (int r4 = 0; r4 < 4; ++r4) {
        int row = row0 + 16*r4 + m;
#pragma unroll
        for (int jj = 0; jj < 4; ++jj) {
            int col = 64*w + 16*jj + 4*qd;
            f32x4 v = a2[r4][jj];
            float4 bv = *(const float4*)(b1 + col);
            v[0] += bv.x; v[1] += bv.y; v[2] += bv.z; v[3] += bv.w;
#pragma unroll
            for (int e = 0; e < 4; ++e)
                v[e] = 0.5f * v[e] * (1.0f + erff(v[e] * 0.70710678118654752f));
            float4 sv = {v[0], v[1], v[2], v[3]};
            *(float4*)(hb + (size_t)row*DFF_ + col) = sv;
        }
    }
}

// ---------------------------------------------------------------------------
// FUSED: FFN2 (+b2, +resid, writes x) + restage + [TAIL=0: next-layer QKV]
//                                               [TAIL=1: fusion att dot]
// (R3's best-measured version.)
// ---------------------------------------------------------------------------
template<int TAIL>
__global__ __launch_bounds__(256)
void ffn2_next_kernel(const float* __restrict__ hb,
                      const short* __restrict__ Whi2, const short* __restrict__ Wlo2,
                      const float* __restrict__ b2,
                      const short* __restrict__ WhiN, const short* __restrict__ WloN,
                      const float* __restrict__ bfv, const float* __restrict__ uf,
                      const float* __restrict__ cfm,
                      const int* __restrict__ kcount, float* __restrict__ x,
                      float* __restrict__ qout,
                      short* __restrict__ khi, short* __restrict__ klo,
                      short* __restrict__ vhiT, short* __restrict__ vloT,
                      float* __restrict__ attb)
{
    const int row0 = blockIdx.x * 64;
    const int bb = row0 >> 11;
    if ((row0 & 2047) >= ((kcount[bb] + 63) & ~63)) return;

    __shared__ short Ahi[64*136];
    __shared__ short Alo[64*136];
    __shared__ float part[64][16];
    const int t = threadIdx.x;
    const int w = t >> 6, lane = t & 63;
    const int m = lane & 15, qd = lane >> 4;

    // ---- FFN2: K=256, two staging phases ----
    f32x4 acc[4][2];
#pragma unroll
    for (int r4 = 0; r4 < 4; ++r4)
#pragma unroll
        for (int j = 0; j < 2; ++j) acc[r4][j] = (f32x4){0,0,0,0};

    for (int kb = 0; kb < DFF_; kb += 128) {
        if (kb) __syncthreads();
#pragma unroll
        for (int i = 0; i < 8; ++i) {
            int r = (t >> 5) + 8*i;
            int c = (t & 31) * 4;
            float4 av = *(const float4*)(hb + (size_t)(row0 + r)*DFF_ + kb + c);
            short4 hi4, lo4;
            split2(av.x, hi4.x, lo4.x);
            split2(av.y, hi4.y, lo4.y);
            split2(av.z, hi4.z, lo4.z);
            split2(av.w, hi4.w, lo4.w);
            *(short4*)&Ahi[r*136 + c] = hi4;
            *(short4*)&Alo[r*136 + c] = lo4;
        }
        __syncthreads();

#pragma unroll
        for (int ks = 0; ks < 4; ++ks) {
            bf16x8 wh[2], wl[2];
#pragma unroll
            for (int j = 0; j < 2; ++j) {
                size_t wi = (size_t)(32*w + 16*j + m)*DFF_ + kb + 32*ks + 8*qd;
                wh[j] = *(const bf16x8*)(Whi2 + wi);
                wl[j] = *(const bf16x8*)(Wlo2 + wi);
            }
#pragma unroll
            for (int r4 = 0; r4 < 4; ++r4) {
                bf16x8 ah = *(const bf16x8*)&Ahi[(16*r4 + m)*136 + 32*ks + 8*qd];
                bf16x8 al = *(const bf16x8*)&Alo[(16*r4 + m)*136 + 32*ks + 8*qd];
#pragma unroll
                for (int j = 0; j < 2; ++j) {
                    acc[r4][j] = __builtin_amdgcn_mfma_f32_16x16x32_bf16(wh[j], ah, acc[r4][j], 0, 0, 0);
                    acc[r4][j] = __builtin_amdgcn_mfma_f32_16x16x32_bf16(wh[j], al, acc[r4][j], 0, 0, 0);
                    acc[r4][j] = __builtin_amdgcn_mfma_f32_16x16x32_bf16(wl[j], ah, acc[r4][j], 0, 0, 0);
                }
            }
        }
    }

    // ---- epilogue: xnew = acc + b2 + x; write x; keep in regs ----
#pragma unroll
    for (int r4 = 0; r4 < 4; ++r4) {
        int row = row0 + 16*r4 + m;
#pragma unroll
        for (int j = 0; j < 2; ++j) {
            int col = 32*w + 16*j + 4*qd;
            float4 bv = *(const float4*)(b2 + col);
            float4 rv = *(const float4*)(x + (size_t)row*D_ + col);
            acc[r4][j][0] += bv.x + rv.x; acc[r4][j][1] += bv.y + rv.y;
            acc[r4][j][2] += bv.z + rv.z; acc[r4][j][3] += bv.w + rv.w;
            float4 sv = {acc[r4][j][0], acc[r4][j][1], acc[r4][j][2], acc[r4][j][3]};
            *(float4*)(x + (size_t)row*D_ + col) = sv;
        }
    }
    __syncthreads();

    // ---- restage xnew hi/lo ----
#pragma unroll
    for (int r4 = 0; r4 < 4; ++r4) {
#pragma unroll
        for (int j = 0; j < 2; ++j) {
            int col = 32*w + 16*j + 4*qd;
            short4 hi4, lo4;
            split2(acc[r4][j][0], hi4.x, lo4.x);
            split2(acc[r4][j][1], hi4.y, lo4.y);
            split2(acc[r4][j][2], hi4.z, lo4.z);
            split2(acc[r4][j][3], hi4.w, lo4.w);
            *(short4*)&Ahi[(16*r4 + m)*136 + col] = hi4;
            *(short4*)&Alo[(16*r4 + m)*136 + col] = lo4;
        }
    }
    __syncthreads();

    if (TAIL == 0) {
#pragma unroll
        for (int sec = 0; sec < 3; ++sec) {
            const short* Wh = WhiN + sec*16384;
            const short* Wl = WloN + sec*16384;
            f32x4 a3[4][2];
#pragma unroll
            for (int r4 = 0; r4 < 4; ++r4)
#pragma unroll
                for (int j = 0; j < 2; ++j) a3[r4][j] = (f32x4){0,0,0,0};
#pragma unroll
            for (int ks = 0; ks < 4; ++ks) {
                bf16x8 wh[2], wl[2];
#pragma unroll
                for (int j = 0; j < 2; ++j) {
                    size_t wi = (size_t)(32*w + 16*j + m)*D_ + 32*ks + 8*qd;
                    wh[j] = *(const bf16x8*)(Wh + wi);
                    wl[j] = *(const bf16x8*)(Wl + wi);
                }
#pragma unroll
                for (int r4 = 0; r4 < 4; ++r4) {
                    bf16x8 ah = *(const bf16x8*)&Ahi[(16*r4 + m)*136 + 32*ks + 8*qd];
                    bf16x8 al = *(const bf16x8*)&Alo[(16*r4 + m)*136 + 32*ks + 8*qd];
#pragma unroll
                    for (int j = 0; j < 2; ++j) {
                        a3[r4][j] = __builtin_amdgcn_mfma_f32_16x16x32_bf16(wh[j], ah, a3[r4][j], 0, 0, 0);
                        a3[r4][j] = __builtin_amdgcn_mfma_f32_16x16x32_bf16(wh[j], al, a3[r4][j], 0, 0, 0);
                        a3[r4][j] = __builtin_amdgcn_mfma_f32_16x16x32_bf16(wl[j], ah, a3[r4][j], 0, 0, 0);
                    }
                }
            }
#pragma unroll
            for (int r4 = 0; r4 < 4; ++r4) {
                int row = row0 + 16*r4 + m;
                int l = row & 2047;
#pragma unroll
                for (int j = 0; j < 2; ++j) {
                    int col = 32*w + 16*j + 4*qd;
                    f32x4 v = a3[r4][j];
                    if (sec == 0) {
                        float4 sv = {v[0], v[1], v[2], v[3]};
                        *(float4*)(qout + (size_t)row*D_ + col) = sv;
                    } else if (sec == 1) {
                        size_t idx = ((size_t)((bb*4 + w)*2048 + l))*32 + (col & 31);
                        short4 hi4, lo4;
                        split2(v[0], hi4.x, lo4.x);
                        split2(v[1], hi4.y, lo4.y);
                        split2(v[2], hi4.z, lo4.z);
                        split2(v[3], hi4.w, lo4.w);
                        *(short4*)(khi + idx) = hi4;
                        *(short4*)(klo + idx) = lo4;
                    } else {
                        size_t basep = (size_t)(bb*4 + w)*32;
#pragma unroll
                        for (int e = 0; e < 4; ++e) {
                            int d = 16*j + 4*qd + e;
                            short hh, ll; split2(v[e], hh, ll);
                            vhiT[(basep + d)*2048 + l] = hh;
                            vloT[(basep + d)*2048 + l] = ll;
                        }
                    }
                }
            }
        }
    } else {
        f32x4 a3[4][2];
#pragma unroll
        for (int r4 = 0; r4 < 4; ++r4)
#pragma unroll
            for (int j = 0; j < 2; ++j) a3[r4][j] = (f32x4){0,0,0,0};
#pragma unroll
        for (int ks = 0; ks < 4; ++ks) {
            bf16x8 wh[2], wl[2];
#pragma unroll
            for (int j = 0; j < 2; ++j) {
                size_t wi = (size_t)(32*w + 16*j + m)*D_ + 32*ks + 8*qd;
                wh[j] = *(const bf16x8*)(WhiN + wi);
                wl[j] = *(const bf16x8*)(WloN + wi);
            }
#pragma unroll
            for (int r4 = 0; r4 < 4; ++r4) {
                bf16x8 ah = *(const bf16x8*)&Ahi[(16*r4 + m)*136 + 32*ks + 8*qd];
                bf16x8 al = *(const bf16x8*)&Alo[(16*r4 + m)*136 + 32*ks + 8*qd];
#pragma unroll
                for (int j = 0; j < 2; ++j) {
                    a3[r4][j] = __builtin_amdgcn_mfma_f32_16x16x32_bf16(wh[j], ah, a3[r4][j], 0, 0, 0);
                    a3[r4][j] = __builtin_amdgcn_mfma_f32_16x16x32_bf16(wh[j], al, a3[r4][j], 0, 0, 0);
                    a3[r4][j] = __builtin_amdgcn_mfma_f32_16x16x32_bf16(wl[j], ah, a3[r4][j], 0, 0, 0);
                }
            }
        }
#pragma unroll
        for (int r4 = 0; r4 < 4; ++r4) {
            float dotp = 0.0f;
#pragma unroll
            for (int j = 0; j < 2; ++j) {
                int col = 32*w + 16*j + 4*qd;
                f32x4 v = a3[r4][j];
                float4 bv = *(const float4*)(bfv + col);
                v[0] += bv.x; v[1] += bv.y; v[2] += bv.z; v[3] += bv.w;
#pragma unroll
                for (int e = 0; e < 4; ++e) v[e] = tanhf(v[e]);
                float4 uv = *(const float4*)(uf + col);
                dotp += v[0]*uv.x + v[1]*uv.y + v[2]*uv.z + v[3]*uv.w;
            }
            part[16*r4 + m][4*w + qd] = dotp;
        }
        __syncthreads();
        if (t < 64) {
            float s = 0.0f;
#pragma unroll
            for (int i = 0; i < 16; ++i) s += part[t][i];
            attb[row0 + t] = s + cfm[row0 + t];
        }
    }
}

// ---------------------------------------------------------------------------
// Pooling
// ---------------------------------------------------------------------------
__global__ __launch_bounds__(256)
void pool_stats_kernel(const float* __restrict__ att, const int* __restrict__ kcount,
                       float* __restrict__ p)
{
    int b = blockIdx.x, t = threadIdx.x;
    int lim = (kcount[b] + 63) & ~63;
    __shared__ float red[4];
    __shared__ float a_s[L_];

    float m = -INFINITY;
    for (int l = t; l < L_; l += 256) {
        float a = (l < lim) ? att[b*L_ + l] : FMINV;
        a_s[l] = a;
        m = fmaxf(m, a);
    }
#pragma unroll
    for (int s = 1; s < 64; s <<= 1) m = fmaxf(m, __shfl_xor(m, s));
    if ((t & 63) == 0) red[t >> 6] = m;
    __syncthreads();
    m = fmaxf(fmaxf(red[0], red[1]), fmaxf(red[2], red[3]));
    __syncthreads();

    float s = 0.0f;
    for (int l = t; l < L_; l += 256) s += __expf(a_s[l] - m);
#pragma unroll
    for (int st = 1; st < 64; st <<= 1) s += __shfl_xor(s, st);
    if ((t & 63) == 0) red[t >> 6] = s;
    __syncthreads();
    s = red[0] + red[1] + red[2] + red[3];
    float inv = 1.0f / s;
    for (int l = t; l < L_; l += 256)
        p[b*L_ + l] = (l < lim) ? __expf(a_s[l] - m) * inv : 0.0f;
}

__global__ __launch_bounds__(128)
void pool_partial_kernel(const float* __restrict__ p, const float* __restrict__ x,
                         float* __restrict__ part)
{
    int c = blockIdx.x, b = blockIdx.y, d = threadIdx.x;
    const float* xb = x + ((size_t)(b*L_ + c*128))*D_ + d;
    const float* pb = p + b*L_ + c*128;
    float acc = 0.0f;
#pragma unroll 4
    for (int i = 0; i < 128; ++i) acc += pb[i] * xb[(size_t)i*D_];
    part[((size_t)b*16 + c)*D_ + d] = acc;
}

// ---------------------------------------------------------------------------
// Head (+inline demographics MLP for row b)
// ---------------------------------------------------------------------------
__global__ __launch_bounds__(256)
void head_kernel(const float* __restrict__ part, const float* __restrict__ demog,
                 const float* __restrict__ Wd1, const float* __restrict__ bd1,
                 const float* __restrict__ Wd2, const float* __restrict__ bd2,
                 const float* __restrict__ Wh, const float* __restrict__ bh,
                 float* __restrict__ out)
{
    int b = blockIdx.x, t = threadIdx.x;
    __shared__ float tss[128];
    __shared__ float hs1[256];
    __shared__ float dems[128];
    if (t < 128) {
        float s = 0.0f;
#pragma unroll
        for (int c = 0; c < 16; ++c) s += part[((size_t)b*16 + c)*D_ + t];
        tss[t] = s;
    }
    {
        float a = bd1[t];
#pragma unroll
        for (int kk = 0; kk < DM_; ++kk) a += demog[b*DM_ + kk] * Wd1[kk*(2*D_) + t];
        hs1[t] = tanhf(a);
    }
    __syncthreads();
    if (t < 128) {
        float a = bd2[t];
        for (int kk = 0; kk < 2*D_; ++kk) a += hs1[kk] * Wd2[kk*D_ + t];
        dems[t] = a;
    }
    __syncthreads();
    if (t >= F_OUT) return;
    float acc = bh[t];
    for (int k2 = 0; k2 < D_; ++k2) acc += tss[k2]  * Wh[k2*F_OUT + t];
    for (int k2 = 0; k2 < D_; ++k2) acc += dems[k2] * Wh[(D_+k2)*F_OUT + t];
    out[b*F_OUT + t] = acc;
}

// ---------------------------------------------------------------------------
extern "C" void kernel_launch(void* const* d_in, const int* in_sizes, int n_in,
                              void* d_out, int out_size, void* d_ws, size_t ws_size,
                              hipStream_t stream)
{
    (void)in_sizes; (void)n_in; (void)out_size; (void)ws_size;
    const float* values       = (const float*)d_in[0];
    const float* times        = (const float*)d_in[1];
    const int*   variables    = (const int*)  d_in[2];
    const int*   input_mask   = (const int*)  d_in[3];
    const float* demographics = (const float*)d_in[4];
    const float* W1t = (const float*)d_in[5];
    const float* b1t = (const float*)d_in[6];
    const float* W2t = (const float*)d_in[7];
    const float* W1v = (const float*)d_in[8];
    const float* b1v = (const float*)d_in[9];
    const float* W2v = (const float*)d_in[10];
    const float* var_table = (const float*)d_in[11];
    const float* Wq  = (const float*)d_in[12];
    const float* Wk  = (const float*)d_in[13];
    const float* Wv  = (const float*)d_in[14];
    const float* Wo  = (const float*)d_in[15];
    const float* W1  = (const float*)d_in[16];
    const float* b1  = (const float*)d_in[17];
    const float* W2  = (const float*)d_in[18];
    const float* b2  = (const float*)d_in[19];
    const float* Wf  = (const float*)d_in[20];
    const float* bfv = (const float*)d_in[21];
    const float* uf  = (const float*)d_in[22];
    const float* Wd1 = (const float*)d_in[23];
    const float* bd1 = (const float*)d_in[24];
    const float* Wd2 = (const float*)d_in[25];
    const float* bd2 = (const float*)d_in[26];
    const float* Wh  = (const float*)d_in[27];
    const float* bhv = (const float*)d_in[28];
    float* out = (float*)d_out;

    float* ws     = (float*)d_ws;
    float* x      = ws;                   // compact rows
    float* qb     = ws + (size_t)SZ_X;
    float* region = ws + (size_t)2*SZ_X;
    short* khi    = (short*)region;
    short* klo    = khi + (size_t)SZ_X;
    short* vhiT   = klo + (size_t)SZ_X;
    short* vloT   = vhiT + (size_t)SZ_X;
    float* attb   = ws + (size_t)4*SZ_X;  // BL_
    float* attp   = attb + BL_;           // BL_
    float* partb  = attp + BL_;           // B_*16*D_
    short* wt_hi  = (short*)(partb + B_*16*D_);  // NL_*WT_TOT + 16384 shorts
    short* wt_lo  = wt_hi + ((size_t)NL_*WT_TOT + 16384);
    int*   posb   = (int*)(wt_lo + ((size_t)NL_*WT_TOT + 16384));
    int*   kcountb= posb + BL_;
    float* cfmb   = (float*)(kcountb + B_ + 3);
    float* opart  = cfmb + BL_;                  // 2*SZ_X
    float* mlm    = opart + (size_t)2*SZ_X;      // B_*H_*2*2048
    float* mll    = mlm + (size_t)B_*H_*2*2048;
    float* hb     = mll + (size_t)B_*H_*2*2048;  // 2*SZ_X (dedicated)
    short* wfhi   = wt_hi + (size_t)NL_*WT_TOT;
    short* wflo   = wt_lo + (size_t)NL_*WT_TOT;

    compact_kernel<<<B_, 256, 0, stream>>>(input_mask, posb, kcountb, cfmb, x);
    embed_kernel<<<BL_, 128, 0, stream>>>(values, times, variables, posb,
                                          W1t, b1t, W2t, W1v, b1v, W2v,
                                          var_table, x);
    split_all_kernel<<<(NL_*131072 + 16384)/256, 256, 0, stream>>>(
        Wq, Wk, Wv, Wo, W1, W2, Wf, wt_hi, wt_lo);

    gemm_qkv_fused<<<dim3(BL_/64, 3), 256, 0, stream>>>(x,
        wt_hi + 0*WT_TOT, wt_lo + 0*WT_TOT, kcountb, qb, khi, klo, vhiT, vloT);

    for (int i = 0; i < NL_; ++i) {
        short* whL = wt_hi + (size_t)i*WT_TOT;
        short* wlL = wt_lo + (size_t)i*WT_TOT;
        attn_mfma_kernel<<<dim3(L_/128, H_*2, B_), 256, 0, stream>>>(qb, khi, klo,
            vhiT, vloT, kcountb, cfmb, opart, mlm, mll);
        wo_ffn1_kernel<<<BL_/64, 256, 0, stream>>>(opart, mlm, mll,
            whL+WT_O, wlL+WT_O, whL+WT_1, wlL+WT_1, b1 + i*DFF_,
            kcountb, x, hb);
        if (i < NL_ - 1) {
            short* whN = wt_hi + (size_t)(i+1)*WT_TOT;
            short* wlN = wt_lo + (size_t)(i+1)*WT_TOT;
            ffn2_next_kernel<0><<<BL_/64, 256, 0, stream>>>(hb,
                whL+WT_2, wlL+WT_2, b2 + i*D_, whN, wlN,
                nullptr, nullptr, nullptr, kcountb, x,
                qb, khi, klo, vhiT, vloT, nullptr);
        } else {
            ffn2_next_kernel<1><<<BL_/64, 256, 0, stream>>>(hb,
                whL+WT_2, wlL+WT_2, b2 + i*D_, wfhi, wflo,
                bfv, uf, cfmb, kcountb, x,
                nullptr, nullptr, nullptr, nullptr, nullptr, attb);
        }
    }

    pool_stats_kernel<<<B_, 256, 0, stream>>>(attb, kcountb, attp);
    pool_partial_kernel<<<dim3(16, B_), 128, 0, stream>>>(attp, x, partb);
    head_kernel<<<B_, 256, 0, stream>>>(partb, demographics, Wd1, bd1, Wd2, bd2,
                                        Wh, bhv, out);
}

// Round 8
// 647.169 us; speedup vs baseline: 1.2413x; 1.2284x over previous
//
#include <hip/hip_runtime.h>
#include <hip/hip_bf16.h>
#include <math.h>

#define B_   16
#define L_   2048
#define D_   128
#define H_   4
#define NL_  4
#define DK_  32
#define DFF_ 256
#define INTD_ 11
#define F_OUT 129
#define DM_  16
#define FMINV (-3.402823466e38f)
#define LOG2E 1.4426950408889634f

#define BL_  (B_*L_)      // 32768
#define SZ_X (BL_*D_)     // 4194304 floats

#define WT_Q 0
#define WT_K 16384
#define WT_V 32768
#define WT_O 49152
#define WT_1 65536
#define WT_2 98304
#define WT_TOT 131072

typedef __attribute__((ext_vector_type(8))) short bf16x8;
typedef __attribute__((ext_vector_type(4))) float f32x4;

#if __has_builtin(__builtin_amdgcn_exp2f)
#define EXP2F(x) __builtin_amdgcn_exp2f(x)
#else
#define EXP2F(x) __expf(0.69314718055994531f*(x))
#endif

static __device__ __forceinline__ short f2bf(float x) {
    union { __hip_bfloat16 h; short s; } u;
    u.h = __float2bfloat16(x);
    return u.s;
}
static __device__ __forceinline__ float bf2f(short s) {
    union { __hip_bfloat16 h; short t; } u;
    u.t = s;
    return __bfloat162float(u.h);
}
static __device__ __forceinline__ void split2(float v, short& h, short& l) {
    h = f2bf(v); l = f2bf(v - bf2f(h));
}
static __device__ __forceinline__ void split_trunc(float v, short& h, short& l) {
    unsigned u = __float_as_uint(v);
    h = (short)(u >> 16);
    float r = v - __uint_as_float(u & 0xffff0000u);
    l = (short)(__float_as_uint(r) >> 16);
}
// Raw workgroup barrier draining LDS only: outstanding GLOBAL loads/stores
// stay in flight (compiler's __syncthreads would emit vmcnt(0) too).
static __device__ __forceinline__ void bar_lgkm() {
    asm volatile("s_waitcnt lgkmcnt(0)" ::: "memory");
    __builtin_amdgcn_s_barrier();
}
// R8: decode flat compacted tile index -> batch b (tp = exclusive prefix of
// per-batch tile counts; uniform scalar loads).
static __device__ __forceinline__ int find_b(const int* __restrict__ tp, int bidx) {
    int b = 0;
    while (bidx >= tp[b+1]) ++b;
    return b;
}

// ---------------------------------------------------------------------------
// Mask compaction + x tail-zero: pos, kcount, cfm; zeroes x rows [Kb,ceil64).
// ---------------------------------------------------------------------------
__global__ __launch_bounds__(256)
void compact_kernel(const int* __restrict__ mask, int* __restrict__ pos,
                    int* __restrict__ kcount, float* __restrict__ cfm,
                    float* __restrict__ x)
{
    int b = blockIdx.x, t = threadIdx.x;
    int lane = t & 63, w = t >> 6;
    __shared__ int wsum[4];
    __shared__ int tot_s;
    int mv[8], loc[8], s = 0;
#pragma unroll
    for (int i = 0; i < 8; ++i) {
        mv[i] = mask[b*L_ + t*8 + i];
        loc[i] = s;
        s += mv[i];
    }
    int v = s;
#pragma unroll
    for (int d = 1; d < 64; d <<= 1) {
        int y = __shfl_up(v, d);
        if (lane >= d) v += y;
    }
    int excl = v - s;
    if (lane == 63) wsum[w] = v;
    __syncthreads();
    int wbase = 0;
    for (int i = 0; i < w; ++i) wbase += wsum[i];
    int base = wbase + excl;
#pragma unroll
    for (int i = 0; i < 8; ++i)
        pos[b*L_ + t*8 + i] = mv[i] ? (base + loc[i]) : -1;
    if (t == 255) { kcount[b] = base + s; tot_s = base + s; }
    __syncthreads();
    int tot = tot_s;
    for (int l = t; l < L_; l += 256) cfm[b*L_ + l] = (l < tot) ? 0.0f : FMINV;
    int end = (tot + 63) & ~63;
    int nz = (end - tot) * D_;
    for (int i = t; i < nz; i += 256)
        x[((size_t)(b*2048 + tot))*D_ + i] = 0.0f;
}

// ---------------------------------------------------------------------------
// R8: per-batch 64-row tile counts -> exclusive prefix (17 entries).
// ---------------------------------------------------------------------------
__global__ __launch_bounds__(64)
void tile_prefix_kernel(const int* __restrict__ kcount, int* __restrict__ tprefix)
{
    if (threadIdx.x == 0) {
        int s = 0;
        for (int b = 0; b < B_; ++b) {
            tprefix[b] = s;
            s += (kcount[b] + 63) >> 6;
        }
        tprefix[B_] = s;
    }
}

// ---------------------------------------------------------------------------
// Embedding with compaction
// ---------------------------------------------------------------------------
__global__ __launch_bounds__(128)
void embed_kernel(const float* __restrict__ values, const float* __restrict__ times,
                  const int* __restrict__ variables, const int* __restrict__ pos,
                  const float* __restrict__ W1t, const float* __restrict__ b1t,
                  const float* __restrict__ W2t,
                  const float* __restrict__ W1v, const float* __restrict__ b1v,
                  const float* __restrict__ W2v,
                  const float* __restrict__ var_table, float* __restrict__ x)
{
    int bl = blockIdx.x;
    int p  = pos[bl];
    if (p < 0) return;
    int t  = threadIdx.x;
    __shared__ float th[INTD_], vh[INTD_];
    if (t < INTD_)                th[t]    = tanhf(times[bl]  * W1t[t]    + b1t[t]);
    if (t >= 64 && t < 64+INTD_)  vh[t-64] = tanhf(values[bl] * W1v[t-64] + b1v[t-64]);
    __syncthreads();
    int var = variables[bl];
    float acc = var_table[var*D_ + t];
#pragma unroll
    for (int i = 0; i < INTD_; ++i)
        acc += th[i]*W2t[i*D_ + t] + vh[i]*W2v[i*D_ + t];
    x[((size_t)((bl >> 11)*2048 + p))*D_ + t] = acc;
}

// ---------------------------------------------------------------------------
// Weight pre-split: all 4 layers + Wf appended at offset NL_*WT_TOT.
// ---------------------------------------------------------------------------
__global__ __launch_bounds__(256)
void split_all_kernel(const float* __restrict__ Wq, const float* __restrict__ Wk,
                      const float* __restrict__ Wv, const float* __restrict__ Wo,
                      const float* __restrict__ W1, const float* __restrict__ W2,
                      const float* __restrict__ Wf,
                      short* __restrict__ hi, short* __restrict__ lo)
{
    int gidx = blockIdx.x*256 + threadIdx.x;
    float v;
    if (gidx < NL_*131072) {
        int layer = gidx >> 17;
        int idx   = gidx & 131071;
        if (idx < 49152) {
            int which = idx >> 14;
            int r = idx & 16383;
            int col = r >> 7, k = r & 127;
            int h = col >> 5, e = col & 31;
            const float* src = ((which == 0) ? Wq : (which == 1) ? Wk : Wv)
                               + (size_t)layer*H_*D_*DK_;
            v = src[(h*D_ + k)*DK_ + e];
        } else if (idx < 65536) {
            int r = idx - 49152;
            int col = r >> 7, k = r & 127;
            v = Wo[(size_t)layer*D_*D_ + k*D_ + col];
        } else if (idx < 98304) {
            int r = idx - 65536;
            int col = r >> 7, k = r & 127;
            v = W1[(size_t)layer*D_*DFF_ + k*DFF_ + col];
        } else {
            int r = idx - 98304;
            int col = r >> 8, k = r & 255;
            v = W2[(size_t)layer*DFF_*D_ + k*D_ + col];
        }
    } else {
        int r = gidx - NL_*131072;      // Wf: 16384 elems, [col][K]
        int col = r >> 7, k = r & 127;
        v = Wf[k*D_ + col];
    }
    short h2, l2; split2(v, h2, l2);
    hi[gidx] = h2; lo[gidx] = l2;
}

// ---------------------------------------------------------------------------
// Fused QKV GEMM (layer 0 only), one weight stream per block (grid.y=3).
// R8: blockIdx.x is a COMPACTED tile index (active blocks contiguous).
// ---------------------------------------------------------------------------
__global__ __launch_bounds__(256)
void gemm_qkv_fused(const float* __restrict__ A, const short* __restrict__ Whi,
                    const short* __restrict__ Wlo, const int* __restrict__ tprefix,
                    float* __restrict__ qout,
                    short* __restrict__ khi, short* __restrict__ klo,
                    short* __restrict__ vhiT, short* __restrict__ vloT)
{
    const int bidx = blockIdx.x;
    if (bidx >= tprefix[B_]) return;
    const int bb = find_b(tprefix, bidx);
    const int row0 = bb*2048 + (bidx - tprefix[bb])*64;
    const int sec = blockIdx.y;

    __shared__ short Ahi[64*136];
    __shared__ short Alo[64*136];
    const int t = threadIdx.x;
    const int w = t >> 6, lane = t & 63;
    const int m = lane & 15, qd = lane >> 4;

#pragma unroll
    for (int i = 0; i < 8; ++i) {
        int r = (t >> 5) + 8*i;
        int c = (t & 31) * 4;
        float4 av = *(const float4*)(A + (size_t)(row0 + r)*D_ + c);
        short4 hi4, lo4;
        split2(av.x, hi4.x, lo4.x);
        split2(av.y, hi4.y, lo4.y);
        split2(av.z, hi4.z, lo4.z);
        split2(av.w, hi4.w, lo4.w);
        *(short4*)&Ahi[r*136 + c] = hi4;
        *(short4*)&Alo[r*136 + c] = lo4;
    }
    __syncthreads();

    const short* Wh = Whi + sec*16384;
    const short* Wl = Wlo + sec*16384;
    f32x4 acc[4][2];
#pragma unroll
    for (int r4 = 0; r4 < 4; ++r4)
#pragma unroll
        for (int j = 0; j < 2; ++j) acc[r4][j] = (f32x4){0,0,0,0};

#pragma unroll
    for (int ks = 0; ks < 4; ++ks) {
        bf16x8 wh[2], wl[2];
#pragma unroll
        for (int j = 0; j < 2; ++j) {
            size_t wi = (size_t)(32*w + 16*j + m)*D_ + 32*ks + 8*qd;
            wh[j] = *(const bf16x8*)(Wh + wi);
            wl[j] = *(const bf16x8*)(Wl + wi);
        }
#pragma unroll
        for (int r4 = 0; r4 < 4; ++r4) {
            bf16x8 ah = *(const bf16x8*)&Ahi[(16*r4 + m)*136 + 32*ks + 8*qd];
            bf16x8 al = *(const bf16x8*)&Alo[(16*r4 + m)*136 + 32*ks + 8*qd];
#pragma unroll
            for (int j = 0; j < 2; ++j) {
                acc[r4][j] = __builtin_amdgcn_mfma_f32_16x16x32_bf16(wh[j], ah, acc[r4][j], 0, 0, 0);
                acc[r4][j] = __builtin_amdgcn_mfma_f32_16x16x32_bf16(wh[j], al, acc[r4][j], 0, 0, 0);
                acc[r4][j] = __builtin_amdgcn_mfma_f32_16x16x32_bf16(wl[j], ah, acc[r4][j], 0, 0, 0);
            }
        }
    }

#pragma unroll
    for (int r4 = 0; r4 < 4; ++r4) {
        int row = row0 + 16*r4 + m;
        int l = row & 2047;
#pragma unroll
        for (int j = 0; j < 2; ++j) {
            int col = 32*w + 16*j + 4*qd;
            f32x4 v = acc[r4][j];
            if (sec == 0) {
                float4 sv = {v[0], v[1], v[2], v[3]};
                *(float4*)(qout + (size_t)row*D_ + col) = sv;
            } else if (sec == 1) {
                size_t idx = ((size_t)((bb*4 + w)*2048 + l))*32 + (col & 31);
                short4 hi4, lo4;
                split2(v[0], hi4.x, lo4.x);
                split2(v[1], hi4.y, lo4.y);
                split2(v[2], hi4.z, lo4.z);
                split2(v[3], hi4.w, lo4.w);
                *(short4*)(khi + idx) = hi4;
                *(short4*)(klo + idx) = lo4;
            } else {
                size_t basep = (size_t)(bb*4 + w)*32;
#pragma unroll
                for (int e = 0; e < 4; ++e) {
                    int d = 16*j + 4*qd + e;
                    short hh, ll; split2(v[e], hh, ll);
                    vhiT[(basep + d)*2048 + l] = hh;
                    vloT[(basep + d)*2048 + l] = ll;
                }
            }
        }
    }
}

// ---------------------------------------------------------------------------
// SPLIT-K MFMA flash attention — R3's best-measured body (95.0 µs), R8:
// blockIdx.x is a COMPACTED (b, qt) index so active blocks are contiguous
// in dispatch order (fixes periodic aliasing of the masked-block pattern
// with the block->CU mapping). grid (512, 8).
// ---------------------------------------------------------------------------
__global__ __launch_bounds__(256)
void attn_mfma_kernel(const float* __restrict__ q,
                      const short* __restrict__ khi, const short* __restrict__ klo,
                      const short* __restrict__ vhiT, const short* __restrict__ vloT,
                      const int* __restrict__ kcount, const int* __restrict__ tprefix,
                      float* __restrict__ opart, float* __restrict__ mlm,
                      float* __restrict__ mll)
{
    __shared__ short KhiS[2][2048];   // [buf][key*32 + dim]   rows 64B, aligned
    __shared__ short KloS[2][2048];
    __shared__ short Vthi[2][2048];   // [buf][d*64 + swz-chunk] rows 128B
    __shared__ short Vtlo[2][2048];
    __shared__ short Ps[4][1024];     // per-wave [m*64 + swz-chunk]

    const int bidx = blockIdx.x;
    if (bidx >= tprefix[B_]) return;
    const int b  = find_b(tprefix, bidx);
    const int qt = bidx - tprefix[b];
    const int h = blockIdx.y & 3, half = blockIdx.y >> 2;

    const int t    = threadIdx.x;
    const int w    = t >> 6;
    const int lane = t & 63;
    const int m    = lane & 15;
    const int qd   = lane >> 4;

    const int Kb = kcount[b];
    const int nt = (Kb + 63) >> 6;
    const int ntH = (nt + 1) >> 1;
    const int kt0 = half * ntH;
    const int kt1 = (kt0 + ntH < nt) ? (kt0 + ntH) : nt;
    const size_t mlbase = (((size_t)(b*4 + h))*2 + half)*2048;

    if (kt0 >= kt1) {
        if (lane < 16) {
            mlm[mlbase + qt*64 + 16*w + lane] = FMINV;
            mll[mlbase + qt*64 + 16*w + lane] = 0.0f;
        }
        return;
    }

    const size_t hd = ((size_t)(b*4 + h))*2048*32;
    const int vd = t >> 3;
    const int vk = t & 7;
    const size_t vbase = ((size_t)(b*4 + h)*32 + vd)*2048 + vk*8;
    const int vw_off = vd*64 + ((vk ^ (vd & 7)) << 3);   // swizzled V slot

    const int qrow = qt*64 + 16*w + m;
    const float* qp = q + ((size_t)(b*L_ + qrow))*D_ + h*DK_ + 8*qd;
    float qf[8];
    *(float4*)&qf[0] = *(const float4*)qp;
    *(float4*)&qf[4] = *(const float4*)(qp + 4);
    bf16x8 qhi, qlo;
#pragma unroll
    for (int j = 0; j < 8; ++j) {
        float qs = qf[j] * LOG2E;
        short hs = f2bf(qs);
        qhi[j] = hs;
        qlo[j] = f2bf(qs - bf2f(hs));
    }

    bf16x8 pkh, pkl, pvh, pvl;
    {
        const size_t gk = hd + (size_t)kt0*64*32 + t*8;
        pkh = *(const bf16x8*)(khi + gk);
        pkl = *(const bf16x8*)(klo + gk);
        pvh = *(const bf16x8*)(vhiT + vbase + (size_t)kt0*64);
        pvl = *(const bf16x8*)(vloT + vbase + (size_t)kt0*64);
    }

    float m_old = -INFINITY, l_run = 0.0f;
    f32x4 o_acc[2] = {{0,0,0,0},{0,0,0,0}};

    for (int kt = kt0; kt < kt1; ++kt) {
        const int buf = kt & 1;
        // ---- stage current tile into LDS[buf] (other waves may still be
        //      computing on LDS[buf^1] — no pre-barrier needed) ----
        *(bf16x8*)&KhiS[buf][t*8] = pkh;
        *(bf16x8*)&KloS[buf][t*8] = pkl;
        *(bf16x8*)&Vthi[buf][vw_off] = pvh;
        *(bf16x8*)&Vtlo[buf][vw_off] = pvl;
        // ---- issue next-tile prefetch; stays in flight across the barrier ----
        if (kt + 1 < kt1) {
            const size_t gk = hd + (size_t)(kt+1)*64*32 + t*8;
            pkh = *(const bf16x8*)(khi + gk);
            pkl = *(const bf16x8*)(klo + gk);
            pvh = *(const bf16x8*)(vhiT + vbase + (size_t)(kt+1)*64);
            pvl = *(const bf16x8*)(vloT + vbase + (size_t)(kt+1)*64);
        }
        // ---- single barrier: drain LDS only (NOT vmcnt) ----
        bar_lgkm();
        __builtin_amdgcn_sched_barrier(0);

        // ---- QK^T ----
        f32x4 sf[4];
#pragma unroll
        for (int k4 = 0; k4 < 4; ++k4) {
            bf16x8 ka = *(const bf16x8*)&KhiS[buf][(16*k4 + m)*32 + 8*qd];
            bf16x8 kl = *(const bf16x8*)&KloS[buf][(16*k4 + m)*32 + 8*qd];
            f32x4 c = {0,0,0,0};
            c = __builtin_amdgcn_mfma_f32_16x16x32_bf16(ka, qhi, c, 0, 0, 0);
            c = __builtin_amdgcn_mfma_f32_16x16x32_bf16(ka, qlo, c, 0, 0, 0);
            c = __builtin_amdgcn_mfma_f32_16x16x32_bf16(kl, qhi, c, 0, 0, 0);
            sf[k4] = c;
        }

        // ---- mask: only the last tile has invalid columns ----
        float sv[16];
        if (kt == nt - 1) {
            const int rel = Kb - kt*64;
#pragma unroll
            for (int k4 = 0; k4 < 4; ++k4)
#pragma unroll
                for (int e = 0; e < 4; ++e)
                    sv[4*k4+e] = sf[k4][e] +
                        (((16*k4 + 4*qd + e) < rel) ? 0.0f : FMINV);
        } else {
#pragma unroll
            for (int k4 = 0; k4 < 4; ++k4)
#pragma unroll
                for (int e = 0; e < 4; ++e)
                    sv[4*k4+e] = sf[k4][e];
        }

        // log-depth max tree
        float mx8[8];
#pragma unroll
        for (int j = 0; j < 8; ++j) mx8[j] = fmaxf(sv[2*j], sv[2*j+1]);
#pragma unroll
        for (int j = 0; j < 4; ++j) mx8[j] = fmaxf(mx8[j], mx8[j+4]);
        float tmax = fmaxf(fmaxf(mx8[0], mx8[1]), fmaxf(mx8[2], mx8[3]));
        tmax = fmaxf(tmax, __shfl_xor(tmax, 16));
        tmax = fmaxf(tmax, __shfl_xor(tmax, 32));
        float mnew  = fmaxf(m_old, tmax);
        float alpha = EXP2F(m_old - mnew);
        float pj[16];
        short pbh[16], pbl[16];
#pragma unroll
        for (int j = 0; j < 16; ++j) {
            float p = EXP2F(sv[j] - mnew);
            pj[j] = p;
            split_trunc(p, pbh[j], pbl[j]);
        }
        // log-depth sum tree
        float ps8[8];
#pragma unroll
        for (int j = 0; j < 8; ++j) ps8[j] = pj[2*j] + pj[2*j+1];
#pragma unroll
        for (int j = 0; j < 4; ++j) ps8[j] = ps8[j] + ps8[j+4];
        float psum = (ps8[0] + ps8[1]) + (ps8[2] + ps8[3]);
        psum += __shfl_xor(psum, 16);
        psum += __shfl_xor(psum, 32);
        l_run = l_run * alpha + psum;
        m_old = mnew;

        // ---- write Phi (swizzled chunks, 8B-aligned short4) ----
#pragma unroll
        for (int k4 = 0; k4 < 4; ++k4) {
            short4 s4h;
            s4h.x = pbh[4*k4+0]; s4h.y = pbh[4*k4+1]; s4h.z = pbh[4*k4+2]; s4h.w = pbh[4*k4+3];
            int chunk = 2*k4 + (qd >> 1);
            int po = m*64 + ((chunk ^ (m & 7)) << 3) + ((qd & 1) << 2);
            *(short4*)&Ps[w][po] = s4h;
        }

        // ---- O rescale: alpha lives per q-row m; rows of o_acc are 4qd+r ----
        {
            float a0 = __shfl(alpha, 4*qd + 0);
            float a1 = __shfl(alpha, 4*qd + 1);
            float a2 = __shfl(alpha, 4*qd + 2);
            float a3 = __shfl(alpha, 4*qd + 3);
            o_acc[0][0]*=a0; o_acc[0][1]*=a1; o_acc[0][2]*=a2; o_acc[0][3]*=a3;
            o_acc[1][0]*=a0; o_acc[1][1]*=a1; o_acc[1][2]*=a2; o_acc[1][3]*=a3;
        }
        // ---- pass 1: Phi·Vhi + Phi·Vlo ----
#pragma unroll
        for (int s = 0; s < 2; ++s) {
#pragma unroll
            for (int tp = 0; tp < 2; ++tp) {
                bf16x8 pah = *(const bf16x8*)&Ps[w][m*64 + (((4*s + qd) ^ (m & 7)) << 3)];
                int vr = (16*tp + m)*64 + (((4*s + qd) ^ (m & 7)) << 3);
                bf16x8 vh = *(const bf16x8*)&Vthi[buf][vr];
                bf16x8 vl = *(const bf16x8*)&Vtlo[buf][vr];
                o_acc[tp] = __builtin_amdgcn_mfma_f32_16x16x32_bf16(pah, vh, o_acc[tp], 0, 0, 0);
                o_acc[tp] = __builtin_amdgcn_mfma_f32_16x16x32_bf16(pah, vl, o_acc[tp], 0, 0, 0);
            }
        }
        // ---- overwrite with Plo (wave-private, in-order DS => WAR-safe) ----
#pragma unroll
        for (int k4 = 0; k4 < 4; ++k4) {
            short4 s4l;
            s4l.x = pbl[4*k4+0]; s4l.y = pbl[4*k4+1]; s4l.z = pbl[4*k4+2]; s4l.w = pbl[4*k4+3];
            int chunk = 2*k4 + (qd >> 1);
            int po = m*64 + ((chunk ^ (m & 7)) << 3) + ((qd & 1) << 2);
            *(short4*)&Ps[w][po] = s4l;
        }
        // ---- pass 2: Plo·Vhi ----
#pragma unroll
        for (int s = 0; s < 2; ++s) {
#pragma unroll
            for (int tp = 0; tp < 2; ++tp) {
                bf16x8 pal = *(const bf16x8*)&Ps[w][m*64 + (((4*s + qd) ^ (m & 7)) << 3)];
                int vr = (16*tp + m)*64 + (((4*s + qd) ^ (m & 7)) << 3);
                bf16x8 vh = *(const bf16x8*)&Vthi[buf][vr];
                o_acc[tp] = __builtin_amdgcn_mfma_f32_16x16x32_bf16(pal, vh, o_acc[tp], 0, 0, 0);
            }
        }
    }

    if (lane < 16) {
        mlm[mlbase + qt*64 + 16*w + lane] = m_old;
        mll[mlbase + qt*64 + 16*w + lane] = l_run;
    }
    float* ob = opart + (size_t)half*SZ_X;
#pragma unroll
    for (int tp = 0; tp < 2; ++tp)
#pragma unroll
        for (int r = 0; r < 4; ++r)
            ob[((size_t)(b*L_ + qt*64 + 16*w + 4*qd + r))*D_ + h*DK_ + 16*tp + m] =
                o_acc[tp][r];
}

// ---------------------------------------------------------------------------
// FUSED: split-K merge + Wo GEMM + resid (writes x) + restage + FFN1 + GELU
// (R3 body; R8: compacted block index.)
// ---------------------------------------------------------------------------
__global__ __launch_bounds__(256)
void wo_ffn1_kernel(const float* __restrict__ opart, const float* __restrict__ mlm,
                    const float* __restrict__ mll,
                    const short* __restrict__ WhiO, const short* __restrict__ WloO,
                    const short* __restrict__ Whi1, const short* __restrict__ Wlo1,
                    const float* __restrict__ b1,
                    const int* __restrict__ tprefix, float* __restrict__ x,
                    float* __restrict__ hb)
{
    const int bidx = blockIdx.x;
    if (bidx >= tprefix[B_]) return;
    const int bb = find_b(tprefix, bidx);
    const int row0 = bb*2048 + (bidx - tprefix[bb])*64;

    __shared__ short Ahi[64*136];
    __shared__ short Alo[64*136];
    const int t = threadIdx.x;
    const int w = t >> 6, lane = t & 63;
    const int m = lane & 15, qd = lane >> 4;

    // ---- stage merged O hi/lo ----
#pragma unroll
    for (int i = 0; i < 8; ++i) {
        int r = (t >> 5) + 8*i;
        int c = (t & 31) * 4;
        int row = row0 + r;
        int l = row & 2047;
        int h = c >> 5;
        size_t i0 = (((size_t)(bb*4 + h))*2 + 0)*2048 + l;
        size_t i1 = i0 + 2048;
        float m0 = mlm[i0], m1 = mlm[i1];
        float l0 = mll[i0], l1 = mll[i1];
        float M  = fmaxf(m0, m1);
        float w0 = EXP2F(m0 - M), w1 = EXP2F(m1 - M);
        float inv = 1.0f / (l0*w0 + l1*w1);
        float s0 = w0 * inv, s1 = w1 * inv;
        float4 o0 = *(const float4*)(opart + (size_t)row*D_ + c);
        float4 o1 = *(const float4*)(opart + (size_t)(BL_ + row)*D_ + c);
        float4 av;
        av.x = s0*o0.x + s1*o1.x;
        av.y = s0*o0.y + s1*o1.y;
        av.z = s0*o0.z + s1*o1.z;
        av.w = s0*o0.w + s1*o1.w;
        short4 hi4, lo4;
        split2(av.x, hi4.x, lo4.x);
        split2(av.y, hi4.y, lo4.y);
        split2(av.z, hi4.z, lo4.z);
        split2(av.w, hi4.w, lo4.w);
        *(short4*)&Ahi[r*136 + c] = hi4;
        *(short4*)&Alo[r*136 + c] = lo4;
    }
    __syncthreads();

    // ---- Wo matmul ----
    f32x4 acc[4][2];
#pragma unroll
    for (int r4 = 0; r4 < 4; ++r4)
#pragma unroll
        for (int j = 0; j < 2; ++j) acc[r4][j] = (f32x4){0,0,0,0};
#pragma unroll
    for (int ks = 0; ks < 4; ++ks) {
        bf16x8 wh[2], wl[2];
#pragma unroll
        for (int j = 0; j < 2; ++j) {
            size_t wi = (size_t)(32*w + 16*j + m)*D_ + 32*ks + 8*qd;
            wh[j] = *(const bf16x8*)(WhiO + wi);
            wl[j] = *(const bf16x8*)(WloO + wi);
        }
#pragma unroll
        for (int r4 = 0; r4 < 4; ++r4) {
            bf16x8 ah = *(const bf16x8*)&Ahi[(16*r4 + m)*136 + 32*ks + 8*qd];
            bf16x8 al = *(const bf16x8*)&Alo[(16*r4 + m)*136 + 32*ks + 8*qd];
#pragma unroll
            for (int j = 0; j < 2; ++j) {
                acc[r4][j] = __builtin_amdgcn_mfma_f32_16x16x32_bf16(wh[j], ah, acc[r4][j], 0, 0, 0);
                acc[r4][j] = __builtin_amdgcn_mfma_f32_16x16x32_bf16(wh[j], al, acc[r4][j], 0, 0, 0);
                acc[r4][j] = __builtin_amdgcn_mfma_f32_16x16x32_bf16(wl[j], ah, acc[r4][j], 0, 0, 0);
            }
        }
    }

    // ---- epilogue: xnew = acc + x; write x; keep in regs ----
#pragma unroll
    for (int r4 = 0; r4 < 4; ++r4) {
        int row = row0 + 16*r4 + m;
#pragma unroll
        for (int j = 0; j < 2; ++j) {
            int col = 32*w + 16*j + 4*qd;
            float4 rv = *(const float4*)(x + (size_t)row*D_ + col);
            acc[r4][j][0] += rv.x; acc[r4][j][1] += rv.y;
            acc[r4][j][2] += rv.z; acc[r4][j][3] += rv.w;
            float4 sv = {acc[r4][j][0], acc[r4][j][1], acc[r4][j][2], acc[r4][j][3]};
            *(float4*)(x + (size_t)row*D_ + col) = sv;
        }
    }
    __syncthreads();

    // ---- restage xnew hi/lo ----
#pragma unroll
    for (int r4 = 0; r4 < 4; ++r4) {
#pragma unroll
        for (int j = 0; j < 2; ++j) {
            int col = 32*w + 16*j + 4*qd;
            short4 hi4, lo4;
            split2(acc[r4][j][0], hi4.x, lo4.x);
            split2(acc[r4][j][1], hi4.y, lo4.y);
            split2(acc[r4][j][2], hi4.z, lo4.z);
            split2(acc[r4][j][3], hi4.w, lo4.w);
            *(short4*)&Ahi[(16*r4 + m)*136 + col] = hi4;
            *(short4*)&Alo[(16*r4 + m)*136 + col] = lo4;
        }
    }
    __syncthreads();

    // ---- FFN1 ----
    f32x4 a2[4][4];
#pragma unroll
    for (int r4 = 0; r4 < 4; ++r4)
#pragma unroll
        for (int jj = 0; jj < 4; ++jj) a2[r4][jj] = (f32x4){0,0,0,0};
#pragma unroll
    for (int ks = 0; ks < 4; ++ks) {
        bf16x8 wh[4], wl[4];
#pragma unroll
        for (int jj = 0; jj < 4; ++jj) {
            size_t wi = (size_t)(64*w + 16*jj + m)*D_ + 32*ks + 8*qd;
            wh[jj] = *(const bf16x8*)(Whi1 + wi);
            wl[jj] = *(const bf16x8*)(Wlo1 + wi);
        }
#pragma unroll
        for (int r4 = 0; r4 < 4; ++r4) {
            bf16x8 ah = *(const bf16x8*)&Ahi[(16*r4 + m)*136 + 32*ks + 8*qd];
            bf16x8 al = *(const bf16x8*)&Alo[(16*r4 + m)*136 + 32*ks + 8*qd];
#pragma unroll
            for (int jj = 0; jj < 4; ++jj) {
                a2[r4][jj] = __builtin_amdgcn_mfma_f32_16x16x32_bf16(wh[jj], ah, a2[r4][jj], 0, 0, 0);
                a2[r4][jj] = __builtin_amdgcn_mfma_f32_16x16x32_bf16(wh[jj], al, a2[r4][jj], 0, 0, 0);
                a2[r4][jj] = __builtin_amdgcn_mfma_f32_16x16x32_bf16(wl[jj], ah, a2[r4][jj], 0, 0, 0);
            }
        }
    }

#pragma unroll
    for (int r4 = 0; r4 < 4; ++r4) {
        int row = row0 + 16*r4 + m;
#pragma unroll
        for (int jj = 0; jj < 4; ++jj) {
            int col = 64*w + 16*jj + 4*qd;
            f32x4 v = a2[r4][jj];
            float4 bv = *(const float4*)(b1 + col);
            v[0] += bv.x; v[1] += bv.y; v[2] += bv.z; v[3] += bv.w;
#pragma unroll
            for (int e = 0; e < 4; ++e)
                v[e] = 0.5f * v[e] * (1.0f + erff(v[e] * 0.70710678118654752f));
            float4 sv = {v[0], v[1], v[2], v[3]};
            *(float4*)(hb + (size_t)row*DFF_ + col) = sv;
        }
    }
}

// ---------------------------------------------------------------------------
// FUSED: FFN2 (+b2, +resid, writes x) + restage + [TAIL=0: next-layer QKV]
//                                               [TAIL=1: fusion att dot]
// (R3 body; R8: compacted block index.)
// ---------------------------------------------------------------------------
template<int TAIL>
__global__ __launch_bounds__(256)
void ffn2_next_kernel(const float* __restrict__ hb,
                      const short* __restrict__ Whi2, const short* __restrict__ Wlo2,
                      const float* __restrict__ b2,
                      const short* __restrict__ WhiN, const short* __restrict__ WloN,
                      const float* __restrict__ bfv, const float* __restrict__ uf,
                      const float* __restrict__ cfm,
                      const int* __restrict__ tprefix, float* __restrict__ x,
                      float* __restrict__ qout,
                      short* __restrict__ khi, short* __restrict__ klo,
                      short* __restrict__ vhiT, short* __restrict__ vloT,
                      float* __restrict__ attb)
{
    const int bidx = blockIdx.x;
    if (bidx >= tprefix[B_]) return;
    const int bb = find_b(tprefix, bidx);
    const int row0 = bb*2048 + (bidx - tprefix[bb])*64;

    __shared__ short Ahi[64*136];
    __shared__ short Alo[64*136];
    __shared__ float part[64][16];
    const int t = threadIdx.x;
    const int w = t >> 6, lane = t & 63;
    const int m = lane & 15, qd = lane >> 4;

    // ---- FFN2: K=256, two staging phases ----
    f32x4 acc[4][2];
#pragma unroll
    for (int r4 = 0; r4 < 4; ++r4)
#pragma unroll
        for (int j = 0; j < 2; ++j) acc[r4][j] = (f32x4){0,0,0,0};

    for (int kb = 0; kb < DFF_; kb += 128) {
        if (kb) __syncthreads();
#pragma unroll
        for (int i = 0; i < 8; ++i) {
            int r = (t >> 5) + 8*i;
            int c = (t & 31) * 4;
            float4 av = *(const float4*)(hb + (size_t)(row0 + r)*DFF_ + kb + c);
            short4 hi4, lo4;
            split2(av.x, hi4.x, lo4.x);
            split2(av.y, hi4.y, lo4.y);
            split2(av.z, hi4.z, lo4.z);
            split2(av.w, hi4.w, lo4.w);
            *(short4*)&Ahi[r*136 + c] = hi4;
            *(short4*)&Alo[r*136 + c] = lo4;
        }
        __syncthreads();

#pragma unroll
        for (int ks = 0; ks < 4; ++ks) {
            bf16x8 wh[2], wl[2];
#pragma unroll
            for (int j = 0; j < 2; ++j) {
                size_t wi = (size_t)(32*w + 16*j + m)*DFF_ + kb + 32*ks + 8*qd;
                wh[j] = *(const bf16x8*)(Whi2 + wi);
                wl[j] = *(const bf16x8*)(Wlo2 + wi);
            }
#pragma unroll
            for (int r4 = 0; r4 < 4; ++r4) {
                bf16x8 ah = *(const bf16x8*)&Ahi[(16*r4 + m)*136 + 32*ks + 8*qd];
                bf16x8 al = *(const bf16x8*)&Alo[(16*r4 + m)*136 + 32*ks + 8*qd];
#pragma unroll
                for (int j = 0; j < 2; ++j) {
                    acc[r4][j] = __builtin_amdgcn_mfma_f32_16x16x32_bf16(wh[j], ah, acc[r4][j], 0, 0, 0);
                    acc[r4][j] = __builtin_amdgcn_mfma_f32_16x16x32_bf16(wh[j], al, acc[r4][j], 0, 0, 0);
                    acc[r4][j] = __builtin_amdgcn_mfma_f32_16x16x32_bf16(wl[j], ah, acc[r4][j], 0, 0, 0);
                }
            }
        }
    }

    // ---- epilogue: xnew = acc + b2 + x; write x; keep in regs ----
#pragma unroll
    for (int r4 = 0; r4 < 4; ++r4) {
        int row = row0 + 16*r4 + m;
#pragma unroll
        for (int j = 0; j < 2; ++j) {
            int col = 32*w + 16*j + 4*qd;
            float4 bv = *(const float4*)(b2 + col);
            float4 rv = *(const float4*)(x + (size_t)row*D_ + col);
            acc[r4][j][0] += bv.x + rv.x; acc[r4][j][1] += bv.y + rv.y;
            acc[r4][j][2] += bv.z + rv.z; acc[r4][j][3] += bv.w + rv.w;
            float4 sv = {acc[r4][j][0], acc[r4][j][1], acc[r4][j][2], acc[r4][j][3]};
            *(float4*)(x + (size_t)row*D_ + col) = sv;
        }
    }
    __syncthreads();

    // ---- restage xnew hi/lo ----
#pragma unroll
    for (int r4 = 0; r4 < 4; ++r4) {
#pragma unroll
        for (int j = 0; j < 2; ++j) {
            int col = 32*w + 16*j + 4*qd;
            short4 hi4, lo4;
            split2(acc[r4][j][0], hi4.x, lo4.x);
            split2(acc[r4][j][1], hi4.y, lo4.y);
            split2(acc[r4][j][2], hi4.z, lo4.z);
            split2(acc[r4][j][3], hi4.w, lo4.w);
            *(short4*)&Ahi[(16*r4 + m)*136 + col] = hi4;
            *(short4*)&Alo[(16*r4 + m)*136 + col] = lo4;
        }
    }
    __syncthreads();

    if (TAIL == 0) {
#pragma unroll
        for (int sec = 0; sec < 3; ++sec) {
            const short* Wh = WhiN + sec*16384;
            const short* Wl = WloN + sec*16384;
            f32x4 a3[4][2];
#pragma unroll
            for (int r4 = 0; r4 < 4; ++r4)
#pragma unroll
                for (int j = 0; j < 2; ++j) a3[r4][j] = (f32x4){0,0,0,0};
#pragma unroll
            for (int ks = 0; ks < 4; ++ks) {
                bf16x8 wh[2], wl[2];
#pragma unroll
                for (int j = 0; j < 2; ++j) {
                    size_t wi = (size_t)(32*w + 16*j + m)*D_ + 32*ks + 8*qd;
                    wh[j] = *(const bf16x8*)(Wh + wi);
                    wl[j] = *(const bf16x8*)(Wl + wi);
                }
#pragma unroll
                for (int r4 = 0; r4 < 4; ++r4) {
                    bf16x8 ah = *(const bf16x8*)&Ahi[(16*r4 + m)*136 + 32*ks + 8*qd];
                    bf16x8 al = *(const bf16x8*)&Alo[(16*r4 + m)*136 + 32*ks + 8*qd];
#pragma unroll
                    for (int j = 0; j < 2; ++j) {
                        a3[r4][j] = __builtin_amdgcn_mfma_f32_16x16x32_bf16(wh[j], ah, a3[r4][j], 0, 0, 0);
                        a3[r4][j] = __builtin_amdgcn_mfma_f32_16x16x32_bf16(wh[j], al, a3[r4][j], 0, 0, 0);
                        a3[r4][j] = __builtin_amdgcn_mfma_f32_16x16x32_bf16(wl[j], ah, a3[r4][j], 0, 0, 0);
                    }
                }
            }
#pragma unroll
            for (int r4 = 0; r4 < 4; ++r4) {
                int row = row0 + 16*r4 + m;
                int l = row & 2047;
#pragma unroll
                for (int j = 0; j < 2; ++j) {
                    int col = 32*w + 16*j + 4*qd;
                    f32x4 v = a3[r4][j];
                    if (sec == 0) {
                        float4 sv = {v[0], v[1], v[2], v[3]};
                        *(float4*)(qout + (size_t)row*D_ + col) = sv;
                    } else if (sec == 1) {
                        size_t idx = ((size_t)((bb*4 + w)*2048 + l))*32 + (col & 31);
                        short4 hi4, lo4;
                        split2(v[0], hi4.x, lo4.x);
                        split2(v[1], hi4.y, lo4.y);
                        split2(v[2], hi4.z, lo4.z);
                        split2(v[3], hi4.w, lo4.w);
                        *(short4*)(khi + idx) = hi4;
                        *(short4*)(klo + idx) = lo4;
                    } else {
                        size_t basep = (size_t)(bb*4 + w)*32;
#pragma unroll
                        for (int e = 0; e < 4; ++e) {
                            int d = 16*j + 4*qd + e;
                            short hh, ll; split2(v[e], hh, ll);
                            vhiT[(basep + d)*2048 + l] = hh;
                            vloT[(basep + d)*2048 + l] = ll;
                        }
                    }
                }
            }
        }
    } else {
        f32x4 a3[4][2];
#pragma unroll
        for (int r4 = 0; r4 < 4; ++r4)
#pragma unroll
            for (int j = 0; j < 2; ++j) a3[r4][j] = (f32x4){0,0,0,0};
#pragma unroll
        for (int ks = 0; ks < 4; ++ks) {
            bf16x8 wh[2], wl[2];
#pragma unroll
            for (int j = 0; j < 2; ++j) {
                size_t wi = (size_t)(32*w + 16*j + m)*D_ + 32*ks + 8*qd;
                wh[j] = *(const bf16x8*)(WhiN + wi);
                wl[j] = *(const bf16x8*)(WloN + wi);
            }
#pragma unroll
            for (int r4 = 0; r4 < 4; ++r4) {
                bf16x8 ah = *(const bf16x8*)&Ahi[(16*r4 + m)*136 + 32*ks + 8*qd];
                bf16x8 al = *(const bf16x8*)&Alo[(16*r4 + m)*136 + 32*ks + 8*qd];
#pragma unroll
                for (int j = 0; j < 2; ++j) {
                    a3[r4][j] = __builtin_amdgcn_mfma_f32_16x16x32_bf16(wh[j], ah, a3[r4][j], 0, 0, 0);
                    a3[r4][j] = __builtin_amdgcn_mfma_f32_16x16x32_bf16(wh[j], al, a3[r4][j], 0, 0, 0);
                    a3[r4][j] = __builtin_amdgcn_mfma_f32_16x16x32_bf16(wl[j], ah, a3[r4][j], 0, 0, 0);
                }
            }
        }
#pragma unroll
        for (int r4 = 0; r4 < 4; ++r4) {
            float dotp = 0.0f;
#pragma unroll
            for (int j = 0; j < 2; ++j) {
                int col = 32*w + 16*j + 4*qd;
                f32x4 v = a3[r4][j];
                float4 bv = *(const float4*)(bfv + col);
                v[0] += bv.x; v[1] += bv.y; v[2] += bv.z; v[3] += bv.w;
#pragma unroll
                for (int e = 0; e < 4; ++e) v[e] = tanhf(v[e]);
                float4 uv = *(const float4*)(uf + col);
                dotp += v[0]*uv.x + v[1]*uv.y + v[2]*uv.z + v[3]*uv.w;
            }
            part[16*r4 + m][4*w + qd] = dotp;
        }
        __syncthreads();
        if (t < 64) {
            float s = 0.0f;
#pragma unroll
            for (int i = 0; i < 16; ++i) s += part[t][i];
            attb[row0 + t] = s + cfm[row0 + t];
        }
    }
}

// ---------------------------------------------------------------------------
// Pooling
// ---------------------------------------------------------------------------
__global__ __launch_bounds__(256)
void pool_stats_kernel(const float* __restrict__ att, const int* __restrict__ kcount,
                       float* __restrict__ p)
{
    int b = blockIdx.x, t = threadIdx.x;
    int lim = (kcount[b] + 63) & ~63;
    __shared__ float red[4];
    __shared__ float a_s[L_];

    float m = -INFINITY;
    for (int l = t; l < L_; l += 256) {
        float a = (l < lim) ? att[b*L_ + l] : FMINV;
        a_s[l] = a;
        m = fmaxf(m, a);
    }
#pragma unroll
    for (int s = 1; s < 64; s <<= 1) m = fmaxf(m, __shfl_xor(m, s));
    if ((t & 63) == 0) red[t >> 6] = m;
    __syncthreads();
    m = fmaxf(fmaxf(red[0], red[1]), fmaxf(red[2], red[3]));
    __syncthreads();

    float s = 0.0f;
    for (int l = t; l < L_; l += 256) s += __expf(a_s[l] - m);
#pragma unroll
    for (int st = 1; st < 64; st <<= 1) s += __shfl_xor(s, st);
    if ((t & 63) == 0) red[t >> 6] = s;
    __syncthreads();
    s = red[0] + red[1] + red[2] + red[3];
    float inv = 1.0f / s;
    for (int l = t; l < L_; l += 256)
        p[b*L_ + l] = (l < lim) ? __expf(a_s[l] - m) * inv : 0.0f;
}

__global__ __launch_bounds__(128)
void pool_partial_kernel(const float* __restrict__ p, const float* __restrict__ x,
                         float* __restrict__ part)
{
    int c = blockIdx.x, b = blockIdx.y, d = threadIdx.x;
    const float* xb = x + ((size_t)(b*L_ + c*128))*D_ + d;
    const float* pb = p + b*L_ + c*128;
    float acc = 0.0f;
#pragma unroll 4
    for (int i = 0; i < 128; ++i) acc += pb[i] * xb[(size_t)i*D_];
    part[((size_t)b*16 + c)*D_ + d] = acc;
}

// ---------------------------------------------------------------------------
// Head (+inline demographics MLP for row b)
// ---------------------------------------------------------------------------
__global__ __launch_bounds__(256)
void head_kernel(const float* __restrict__ part, const float* __restrict__ demog,
                 const float* __restrict__ Wd1, const float* __restrict__ bd1,
                 const float* __restrict__ Wd2, const float* __restrict__ bd2,
                 const float* __restrict__ Wh, const float* __restrict__ bh,
                 float* __restrict__ out)
{
    int b = blockIdx.x, t = threadIdx.x;
    __shared__ float tss[128];
    __shared__ float hs1[256];
    __shared__ float dems[128];
    if (t < 128) {
        float s = 0.0f;
#pragma unroll
        for (int c = 0; c < 16; ++c) s += part[((size_t)b*16 + c)*D_ + t];
        tss[t] = s;
    }
    {
        float a = bd1[t];
#pragma unroll
        for (int kk = 0; kk < DM_; ++kk) a += demog[b*DM_ + kk] * Wd1[kk*(2*D_) + t];
        hs1[t] = tanhf(a);
    }
    __syncthreads();
    if (t < 128) {
        float a = bd2[t];
        for (int kk = 0; kk < 2*D_; ++kk) a += hs1[kk] * Wd2[kk*D_ + t];
        dems[t] = a;
    }
    __syncthreads();
    if (t >= F_OUT) return;
    float acc = bh[t];
    for (int k2 = 0; k2 < D_; ++k2) acc += tss[k2]  * Wh[k2*F_OUT + t];
    for (int k2 = 0; k2 < D_; ++k2) acc += dems[k2] * Wh[(D_+k2)*F_OUT + t];
    out[b*F_OUT + t] = acc;
}

// ---------------------------------------------------------------------------
extern "C" void kernel_launch(void* const* d_in, const int* in_sizes, int n_in,
                              void* d_out, int out_size, void* d_ws, size_t ws_size,
                              hipStream_t stream)
{
    (void)in_sizes; (void)n_in; (void)out_size; (void)ws_size;
    const float* values       = (const float*)d_in[0];
    const float* times        = (const float*)d_in[1];
    const int*   variables    = (const int*)  d_in[2];
    const int*   input_mask   = (const int*)  d_in[3];
    const float* demographics = (const float*)d_in[4];
    const float* W1t = (const float*)d_in[5];
    const float* b1t = (const float*)d_in[6];
    const float* W2t = (const float*)d_in[7];
    const float* W1v = (const float*)d_in[8];
    const float* b1v = (const float*)d_in[9];
    const float* W2v = (const float*)d_in[10];
    const float* var_table = (const float*)d_in[11];
    const float* Wq  = (const float*)d_in[12];
    const float* Wk  = (const float*)d_in[13];
    const float* Wv  = (const float*)d_in[14];
    const float* Wo  = (const float*)d_in[15];
    const float* W1  = (const float*)d_in[16];
    const float* b1  = (const float*)d_in[17];
    const float* W2  = (const float*)d_in[18];
    const float* b2  = (const float*)d_in[19];
    const float* Wf  = (const float*)d_in[20];
    const float* bfv = (const float*)d_in[21];
    const float* uf  = (const float*)d_in[22];
    const float* Wd1 = (const float*)d_in[23];
    const float* bd1 = (const float*)d_in[24];
    const float* Wd2 = (const float*)d_in[25];
    const float* bd2 = (const float*)d_in[26];
    const float* Wh  = (const float*)d_in[27];
    const float* bhv = (const float*)d_in[28];
    float* out = (float*)d_out;

    float* ws     = (float*)d_ws;
    float* x      = ws;                   // compact rows
    float* qb     = ws + (size_t)SZ_X;
    float* region = ws + (size_t)2*SZ_X;
    short* khi    = (short*)region;
    short* klo    = khi + (size_t)SZ_X;
    short* vhiT   = klo + (size_t)SZ_X;
    short* vloT   = vhiT + (size_t)SZ_X;
    float* attb   = ws + (size_t)4*SZ_X;  // BL_
    float* attp   = attb + BL_;           // BL_
    float* partb  = attp + BL_;           // B_*16*D_
    short* wt_hi  = (short*)(partb + B_*16*D_);  // NL_*WT_TOT + 16384 shorts
    short* wt_lo  = wt_hi + ((size_t)NL_*WT_TOT + 16384);
    int*   posb   = (int*)(wt_lo + ((size_t)NL_*WT_TOT + 16384));
    int*   kcountb= posb + BL_;
    int*   tprefb = kcountb + B_;                // 17 ints (pad to 40 total)
    float* cfmb   = (float*)(kcountb + 40);
    float* opart  = cfmb + BL_;                  // 2*SZ_X
    float* mlm    = opart + (size_t)2*SZ_X;      // B_*H_*2*2048
    float* mll    = mlm + (size_t)B_*H_*2*2048;
    float* hb     = mll + (size_t)B_*H_*2*2048;  // 2*SZ_X (dedicated)
    short* wfhi   = wt_hi + (size_t)NL_*WT_TOT;
    short* wflo   = wt_lo + (size_t)NL_*WT_TOT;

    compact_kernel<<<B_, 256, 0, stream>>>(input_mask, posb, kcountb, cfmb, x);
    tile_prefix_kernel<<<1, 64, 0, stream>>>(kcountb, tprefb);
    embed_kernel<<<BL_, 128, 0, stream>>>(values, times, variables, posb,
                                          W1t, b1t, W2t, W1v, b1v, W2v,
                                          var_table, x);
    split_all_kernel<<<(NL_*131072 + 16384)/256, 256, 0, stream>>>(
        Wq, Wk, Wv, Wo, W1, W2, Wf, wt_hi, wt_lo);

    gemm_qkv_fused<<<dim3(512, 3), 256, 0, stream>>>(x,
        wt_hi + 0*WT_TOT, wt_lo + 0*WT_TOT, tprefb, qb, khi, klo, vhiT, vloT);

    for (int i = 0; i < NL_; ++i) {
        short* whL = wt_hi + (size_t)i*WT_TOT;
        short* wlL = wt_lo + (size_t)i*WT_TOT;
        attn_mfma_kernel<<<dim3(512, H_*2), 256, 0, stream>>>(qb, khi, klo,
            vhiT, vloT, kcountb, tprefb, opart, mlm, mll);
        wo_ffn1_kernel<<<512, 256, 0, stream>>>(opart, mlm, mll,
            whL+WT_O, wlL+WT_O, whL+WT_1, wlL+WT_1, b1 + i*DFF_,
            tprefb, x, hb);
        if (i < NL_ - 1) {
            short* whN = wt_hi + (size_t)(i+1)*WT_TOT;
            short* wlN = wt_lo + (size_t)(i+1)*WT_TOT;
            ffn2_next_kernel<0><<<512, 256, 0, stream>>>(hb,
                whL+WT_2, wlL+WT_2, b2 + i*D_, whN, wlN,
                nullptr, nullptr, nullptr, tprefb, x,
                qb, khi, klo, vhiT, vloT, nullptr);
        } else {
            ffn2_next_kernel<1><<<512, 256, 0, stream>>>(hb,
                whL+WT_2, wlL+WT_2, b2 + i*D_, wfhi, wflo,
                bfv, uf, cfmb, tprefb, x,
                nullptr, nullptr, nullptr, nullptr, nullptr, attb);
        }
    }

    pool_stats_kernel<<<B_, 256, 0, stream>>>(attb, kcountb, attp);
    pool_partial_kernel<<<dim3(16, B_), 128, 0, stream>>>(attp, x, partb);
    head_kernel<<<B_, 256, 0, stream>>>(partb, demographics, Wd1, bd1, Wd2, bd2,
                                        Wh, bhv, out);
}